// Round 9
// baseline (1149.513 us; speedup 1.0000x reference)
//
#include <hip/hip_runtime.h>
#include <hip/hip_fp16.h>
#include <float.h>
#include <math.h>

#define N_NODES 50000
#define N_EDGES 500000
#define TT 3
#define RR 4
#define HH 8
#define NHID 128
#define NLAYER 2
#define DIN_ 166
#define MAXT_ 240
#define DKH 16
#define NPB 16

// -------------------- setup kernels --------------------

// Sinusoid RTE table, computed in f64 to match numpy, cast to f32.
__global__ void k_sin_table(float* __restrict__ tab) {
    int idx = blockIdx.x * blockDim.x + threadIdx.x;
    if (idx >= MAXT_ * 64) return;
    int p = idx / 64, i2 = idx % 64;
    const double c = -9.210340371976184 / 128.0;   // -ln(10000)/NH
    double div = exp((double)(2 * i2) * c);
    double a = (double)p * div;
    const double s128 = 0.08838834764831845;       // 1/sqrt(128)
    tab[p * NHID + 2 * i2]     = (float)(sin(a) * s128);
    tab[p * NHID + 2 * i2 + 1] = (float)(cos(a) * s128);
}

// Bin nodes by type (wave-aggregated atomics: 3 atomics per wave).
__global__ void k_bin(const int* __restrict__ ntype, int* __restrict__ cnt,
                      int* __restrict__ lists) {
    int n = blockIdx.x * 256 + threadIdx.x;
    int t = (n < N_NODES) ? ntype[n] : -1;
    int lane = threadIdx.x & 63;
    #pragma unroll
    for (int tt = 0; tt < TT; ++tt) {
        unsigned long long mask = __ballot(t == tt);
        if (mask) {
            int leader = (int)__ffsll(mask) - 1;
            int base = 0;
            if (lane == leader) base = atomicAdd(&cnt[tt], __popcll(mask));
            base = __shfl(base, leader);
            if (t == tt) {
                int rank = __popcll(mask & ((1ULL << lane) - 1ULL));
                lists[tt * N_NODES + base + rank] = n;
            }
        }
    }
}

// -------------------- CSR build (once; edge_index constant across layers) ---

__global__ void k_deg(const int* __restrict__ tgt, int* __restrict__ deg) {
    int e = blockIdx.x * 256 + threadIdx.x;
    if (e < N_EDGES) atomicAdd(&deg[tgt[e]], 1);
}

// single-block exclusive scan: rowptr[0]=0, rowptr[i+1]=sum deg[0..i]
__global__ void k_scan(const int* __restrict__ deg, int* __restrict__ rowptr) {
    __shared__ int wsum[16];
    __shared__ int carry_s;
    int tid = threadIdx.x;           // 1024
    int lane = tid & 63, wid = tid >> 6;
    if (tid == 0) { carry_s = 0; rowptr[0] = 0; }
    __syncthreads();
    for (int base = 0; base < N_NODES; base += 1024) {
        int idx = base + tid;
        int x = (idx < N_NODES) ? deg[idx] : 0;
        #pragma unroll
        for (int off = 1; off < 64; off <<= 1) {
            int y = __shfl_up(x, off, 64);
            if (lane >= off) x += y;
        }
        if (lane == 63) wsum[wid] = x;
        __syncthreads();
        if (wid == 0) {
            int w = (lane < 16) ? wsum[lane] : 0;
            #pragma unroll
            for (int off = 1; off < 16; off <<= 1) {
                int y = __shfl_up(w, off, 64);
                if (lane >= off) w += y;
            }
            if (lane < 16) wsum[lane] = w;
        }
        __syncthreads();
        int waveoff = (wid > 0) ? wsum[wid - 1] : 0;
        int incl = carry_s + waveoff + x;
        if (idx < N_NODES) rowptr[idx + 1] = incl;
        __syncthreads();
        if (tid == 1023) carry_s = incl;
        __syncthreads();
    }
}

// Fill CSR-ordered edge attribute arrays (replaces elist indirection):
// sE = src node, gE = target node, attr = (etype<<12)|(etime*TT + ntype[src]).
__global__ void k_fill(const int* __restrict__ src, const int* __restrict__ tgt,
                       const int* __restrict__ etype, const int* __restrict__ etime,
                       const int* __restrict__ ntype, int* __restrict__ cursor,
                       int* __restrict__ sE, int* __restrict__ attr,
                       int* __restrict__ gE) {
    int e = blockIdx.x * 256 + threadIdx.x;
    if (e >= N_EDGES) return;
    int g = tgt[e];
    int s = src[e];
    int r = etype[e];
    int tm = etime[e];
    int t = ntype[s];
    int p = atomicAdd(&cursor[g], 1);
    sE[p] = s;
    attr[p] = (r << 12) | (tm * TT + t);
    gE[p] = g;
}

// -------------------- node-level linears (type-binned) --------------------

__global__ void k_adapter(const float* __restrict__ x, const int* __restrict__ cnt,
                          const int* __restrict__ lists,
                          const float* __restrict__ W, const float* __restrict__ b,
                          float* __restrict__ h) {
    int t = blockIdx.y;
    int c = cnt[t];
    int i0 = blockIdx.x * NPB;
    if (i0 >= c) return;
    int j = threadIdx.x;
    __shared__ float xs[NPB][DIN_];
    __shared__ int nidx[NPB];
    if (j < NPB) nidx[j] = (i0 + j < c) ? lists[t * N_NODES + i0 + j] : -1;
    __syncthreads();
    int nr[NPB];
    #pragma unroll
    for (int m = 0; m < NPB; ++m) nr[m] = nidx[m];
    #pragma unroll
    for (int m = 0; m < NPB; ++m) {
        int n = nr[m];
        for (int d = j; d < DIN_; d += 128)
            xs[m][d] = (n >= 0) ? x[(size_t)n * DIN_ + d] : 0.f;
    }
    __syncthreads();
    const float* Wt = W + (size_t)t * DIN_ * NHID;
    float bj = b[t * NHID + j];
    float acc[NPB];
    #pragma unroll
    for (int m = 0; m < NPB; ++m) acc[m] = bj;
    for (int d = 0; d < DIN_; ++d) {
        float w = Wt[d * NHID + j];
        #pragma unroll
        for (int m = 0; m < NPB; ++m) acc[m] = fmaf(xs[m][d], w, acc[m]);
    }
    #pragma unroll
    for (int m = 0; m < NPB; ++m) {
        int n = nr[m];
        if (n >= 0) h[(size_t)n * NHID + j] = tanhf(acc[m]);
    }
}

// hk/q/hv written as fp16 (gather tables for the edge kernels).
__global__ void k_node_lin(const float* __restrict__ h, const int* __restrict__ cnt,
                           const int* __restrict__ lists,
                           const float* __restrict__ Wk, const float* __restrict__ bk,
                           const float* __restrict__ Wq, const float* __restrict__ bq,
                           const float* __restrict__ Wv, const float* __restrict__ bv,
                           __half* __restrict__ hk16, __half* __restrict__ q16,
                           __half* __restrict__ hv16) {
    int t = blockIdx.y;
    int c = cnt[t];
    int i0 = blockIdx.x * NPB;
    if (i0 >= c) return;
    int j = threadIdx.x;
    __shared__ float hs[NPB][NHID];
    __shared__ int nidx[NPB];
    if (j < NPB) nidx[j] = (i0 + j < c) ? lists[t * N_NODES + i0 + j] : -1;
    __syncthreads();
    int nr[NPB];
    #pragma unroll
    for (int m = 0; m < NPB; ++m) nr[m] = nidx[m];
    #pragma unroll
    for (int m = 0; m < NPB; ++m)
        hs[m][j] = (nr[m] >= 0) ? h[(size_t)nr[m] * NHID + j] : 0.f;
    __syncthreads();
    const float* WkT = Wk + (size_t)t * NHID * NHID;
    const float* WqT = Wq + (size_t)t * NHID * NHID;
    const float* WvT = Wv + (size_t)t * NHID * NHID;
    float ak[NPB], aq[NPB], av[NPB];
    float bkj = bk[t * NHID + j], bqj = bq[t * NHID + j], bvj = bv[t * NHID + j];
    #pragma unroll
    for (int m = 0; m < NPB; ++m) { ak[m] = bkj; aq[m] = bqj; av[m] = bvj; }
    for (int i = 0; i < NHID; ++i) {
        float wk = WkT[i * NHID + j];
        float wq = WqT[i * NHID + j];
        float wv = WvT[i * NHID + j];
        #pragma unroll
        for (int m = 0; m < NPB; ++m) {
            float hi = hs[m][i];
            ak[m] = fmaf(hi, wk, ak[m]);
            aq[m] = fmaf(hi, wq, aq[m]);
            av[m] = fmaf(hi, wv, av[m]);
        }
    }
    #pragma unroll
    for (int m = 0; m < NPB; ++m) {
        int n = nr[m];
        if (n >= 0) {
            hk16[(size_t)n * NHID + j] = __float2half(ak[m]);
            q16 [(size_t)n * NHID + j] = __float2half(aq[m]);
            hv16[(size_t)n * NHID + j] = __float2half(av[m]);
        }
    }
}

__global__ void k_out(const float* __restrict__ agg, const float* __restrict__ hin,
                      const int* __restrict__ cnt, const int* __restrict__ lists,
                      const float* __restrict__ aW, const float* __restrict__ ab,
                      const float* __restrict__ skp, float* __restrict__ hout) {
    int t = blockIdx.y;
    int c = cnt[t];
    int i0 = blockIdx.x * NPB;
    if (i0 >= c) return;
    int j = threadIdx.x;
    __shared__ float gs[NPB][NHID];
    __shared__ int nidx[NPB];
    if (j < NPB) nidx[j] = (i0 + j < c) ? lists[t * N_NODES + i0 + j] : -1;
    __syncthreads();
    int nr[NPB];
    #pragma unroll
    for (int m = 0; m < NPB; ++m) nr[m] = nidx[m];
    #pragma unroll
    for (int m = 0; m < NPB; ++m) {
        int n = nr[m];
        float xv = (n >= 0) ? agg[(size_t)n * NHID + j] : 0.f;
        gs[m][j] = 0.5f * xv * (1.f + erff(xv * 0.7071067811865476f));
    }
    __syncthreads();
    const float* Wt = aW + (size_t)t * NHID * NHID;
    float bj = ab[t * NHID + j];
    float acc[NPB];
    #pragma unroll
    for (int m = 0; m < NPB; ++m) acc[m] = bj;
    for (int i = 0; i < NHID; ++i) {
        float w = Wt[i * NHID + j];
        #pragma unroll
        for (int m = 0; m < NPB; ++m) acc[m] = fmaf(gs[m][i], w, acc[m]);
    }
    float alpha = 1.f / (1.f + expf(-skp[t]));
    #pragma unroll
    for (int m = 0; m < NPB; ++m) {
        int n = nr[m];
        if (n >= 0)
            hout[(size_t)n * NHID + j] =
                acc[m] * alpha + hin[(size_t)n * NHID + j] * (1.f - alpha);
    }
}

// -------------------- tiny RTE projections --------------------

__global__ void k_rte_proj(const float* __restrict__ tab, const float* __restrict__ rteW,
                           const float* __restrict__ rteb, float* __restrict__ proj) {
    int p = blockIdx.x;
    int j = threadIdx.x;
    __shared__ float ts[NHID];
    ts[j] = tab[p * NHID + j];
    __syncthreads();
    float acc = rteb[j];
    for (int i = 0; i < NHID; ++i) acc = fmaf(ts[i], rteW[i * NHID + j], acc);
    proj[p * NHID + j] = acc;
}

// RK written fp16 (k_att gather); RV stays fp32 (k_csr adds in f32).
__global__ void k_rkv(const float* __restrict__ proj, const float* __restrict__ kW,
                      const float* __restrict__ vW, __half* __restrict__ RK16,
                      float* __restrict__ RV) {
    int p = blockIdx.x, t = blockIdx.y;
    int j = threadIdx.x;
    __shared__ float ps[NHID];
    ps[j] = proj[p * NHID + j];
    __syncthreads();
    const float* Wk = kW + (size_t)t * NHID * NHID;
    const float* Wv = vW + (size_t)t * NHID * NHID;
    float ak = 0.f, av = 0.f;
    for (int i = 0; i < NHID; ++i) {
        float pi = ps[i];
        ak = fmaf(pi, Wk[i * NHID + j], ak);
        av = fmaf(pi, Wv[i * NHID + j], av);
    }
    RK16[((size_t)p * TT + t) * NHID + j] = __float2half(ak);
    RV[((size_t)p * TT + t) * NHID + j] = av;
}

// -------------------- NEW: node-level q-side relation transform --------------

// u3[n][r][h*16+f] = sum_d rel_att[r][h][d][f] * q[n][h*16+d]
// Grid (N/16, RR), 128 threads. A slice in 16 registers; q exchanged via
// 16-lane shuffles. Dense, coalesced, 410M FMA total — off the edge path.
__global__ __launch_bounds__(128) void k_qrel(
        const __half* __restrict__ q16, const float* __restrict__ rel_att,
        __half* __restrict__ u316) {
    int j = threadIdx.x;
    int r = blockIdx.y;
    int h = j >> 4, f = j & 15;
    int i0 = blockIdx.x * NPB;
    int lanebase = j & 48;
    float Areg[DKH];
    const float* A = rel_att + ((r * HH + h) << 8) + f;
    #pragma unroll
    for (int d = 0; d < DKH; ++d) Areg[d] = A[d * 16];
    #pragma unroll
    for (int m = 0; m < NPB; ++m) {
        int n = i0 + m;
        float qv = __half2float(q16[(size_t)n * NHID + j]);
        float u = 0.f;
        #pragma unroll
        for (int d = 0; d < DKH; ++d)
            u = fmaf(__shfl(qv, lanebase + d, 64), Areg[d], u);
        u316[((size_t)n * RR + r) * NHID + j] = __float2half(u);
    }
}

// -------------------- edge pass 1: attention scores --------------------

// att[e,h] = ((hk[s]+RK[row]) . u3[g,r])[h] * pri / 4 — pure dot product,
// no LDS, 32 FMA per (e,h). idx = k*8+h keeps row loads lane-coalesced;
// CSR order makes u3[g*4+r] L1-hot across consecutive edges.
__global__ __launch_bounds__(256) void k_att(
        const __half* __restrict__ hk16, const __half* __restrict__ u316,
        const __half* __restrict__ RK16,
        const int* __restrict__ sE, const int* __restrict__ attr,
        const int* __restrict__ gE,
        const float* __restrict__ rel_pri, float* __restrict__ att2) {
    int idx = blockIdx.x * 256 + threadIdx.x;
    if (idx >= N_EDGES * HH) return;
    int k = idx >> 3, h = idx & 7;
    int s = sE[k];
    int a = attr[k];
    int r = a >> 12, row = a & 4095;
    int g = gE[k];
    const __half2* hk2 = (const __half2*)hk16 + (size_t)s * 64 + h * 8;
    const __half2* rk2 = (const __half2*)RK16 + (size_t)row * 64 + h * 8;
    const __half2* u2  = (const __half2*)u316 + ((size_t)g * RR + r) * 64 + h * 8;
    float acc = 0.f;
    #pragma unroll
    for (int i = 0; i < 8; ++i) {
        float2 fa = __half22float2(hk2[i]);
        float2 fb = __half22float2(rk2[i]);
        float2 fu = __half22float2(u2[i]);
        acc = fmaf(fa.x + fb.x, fu.x, acc);
        acc = fmaf(fa.y + fb.y, fu.y, acc);
    }
    acc *= rel_pri[r * HH + h] * 0.25f;
    att2[(size_t)h * N_EDGES + k] = acc;
}

// -------------------- edge pass 2: CSR softmax + aggregate --------------------

// One 128-thread block per target node; thread j = h*16+f owns output dim j.
__global__ __launch_bounds__(128) void k_csr(
        const __half* __restrict__ hv16, const float* __restrict__ RV,
        float* __restrict__ att2,
        const int* __restrict__ rowptr, const int* __restrict__ sE,
        const int* __restrict__ attr,
        const float* __restrict__ rel_msg, float* __restrict__ agg) {
    int n = blockIdx.x;
    int tid = threadIdx.x;
    int h = tid >> 4, f = tid & 15;
    int beg = rowptr[n], end = rowptr[n + 1];
    float* ap = att2 + (size_t)h * N_EDGES;

    // loop1: segment max for head h (16 lanes cooperate).
    float m = -FLT_MAX;
    for (int k = beg + f; k < end; k += 16) m = fmaxf(m, ap[k]);
    #pragma unroll
    for (int mask = 1; mask <= 8; mask <<= 1)
        m = fmaxf(m, __shfl_xor(m, mask, 64));

    // loop2: ex = expf(a-m), store back, accumulate denominator.
    float ssum = 0.f;
    for (int k = beg + f; k < end; k += 16) {
        float ex = expf(ap[k] - m);
        ap[k] = ex;
        ssum += ex;
    }
    #pragma unroll
    for (int mask = 1; mask <= 8; mask <<= 1)
        ssum += __shfl_xor(ssum, mask, 64);
    float rden = 1.f / fmaxf(ssum, 1e-9f);
    __syncthreads();   // make loop2's global writes visible to all lanes

    // Phase B: per-relation unnormalized weighted sums at dim tid.
    float a0 = 0.f, a1 = 0.f, a2 = 0.f, a3 = 0.f;
    #pragma unroll 2
    for (int k = beg; k < end; ++k) {
        int s = sE[k];
        int a = attr[k];
        int r = a >> 12, row = a & 4095;
        float vvt = __half2float(hv16[(size_t)s * NHID + tid])
                    + RV[(size_t)row * NHID + tid];
        float wv = ap[k] * vvt;
        a0 += (r == 0) ? wv : 0.f;
        a1 += (r == 1) ? wv : 0.f;
        a2 += (r == 2) ? wv : 0.f;
        a3 += (r == 3) ? wv : 0.f;
    }

    // Epilogue: agg[n][h*16+f] = rden * sum_r sum_d M_r[h][d][f] * a_r[h*16+d].
    int lanebase = tid & 48;
    float out = 0.f;
    #pragma unroll
    for (int r = 0; r < RR; ++r) {
        float ar = (r == 0) ? a0 : (r == 1) ? a1 : (r == 2) ? a2 : a3;
        const float* M = rel_msg + ((r * HH + h) << 8) + f;
        #pragma unroll
        for (int d = 0; d < DKH; ++d) {
            float vd = __shfl(ar, lanebase + d, 64);
            out = fmaf(vd, M[d * 16], out);
        }
    }
    agg[(size_t)n * NHID + tid] = out * rden;
}

// -------------------- launch --------------------

extern "C" void kernel_launch(void* const* d_in, const int* in_sizes, int n_in,
                              void* d_out, int out_size, void* d_ws, size_t ws_size,
                              hipStream_t stream) {
    const float* node_feature = (const float*)d_in[0];
    const int*   node_type    = (const int*)d_in[1];
    const int*   edge_time    = (const int*)d_in[2];
    const int*   edge_index   = (const int*)d_in[3];
    const int*   edge_type    = (const int*)d_in[4];
    const float* adapt_W = (const float*)d_in[5];
    const float* adapt_b = (const float*)d_in[6];
    const float* kW = (const float*)d_in[7];
    const float* kb = (const float*)d_in[8];
    const float* qW = (const float*)d_in[9];
    const float* qb = (const float*)d_in[10];
    const float* vW = (const float*)d_in[11];
    const float* vb = (const float*)d_in[12];
    const float* aW = (const float*)d_in[13];
    const float* ab = (const float*)d_in[14];
    const float* rel_att = (const float*)d_in[15];
    const float* rel_msg = (const float*)d_in[16];
    const float* rel_pri = (const float*)d_in[17];
    const float* skip = (const float*)d_in[18];
    const float* rteW = (const float*)d_in[19];
    const float* rteb = (const float*)d_in[20];

    const int* src = edge_index;             // edge_index[0][:]
    const int* tgt = edge_index + N_EDGES;   // edge_index[1][:]

    float* ws = (float*)d_ws;
    float* hA   = ws; ws += (size_t)N_NODES * NHID;
    float* hB   = ws; ws += (size_t)N_NODES * NHID;
    float* agg  = ws; ws += (size_t)N_NODES * NHID;
    float* att2 = ws; ws += (size_t)N_EDGES * HH;
    float* tab  = ws; ws += MAXT_ * NHID;
    float* proj = ws; ws += MAXT_ * NHID;
    float* RV   = ws; ws += MAXT_ * TT * NHID;
    __half* hk16 = (__half*)ws; ws += (size_t)N_NODES * NHID / 2;
    __half* q16  = (__half*)ws; ws += (size_t)N_NODES * NHID / 2;
    __half* hv16 = (__half*)ws; ws += (size_t)N_NODES * NHID / 2;
    __half* RK16 = (__half*)ws; ws += (size_t)MAXT_ * TT * NHID / 2;
    __half* u316 = (__half*)ws; ws += (size_t)N_NODES * RR * NHID / 2;
    int*   deg    = (int*)ws; ws += N_NODES;
    int*   rowptr = (int*)ws; ws += N_NODES + 1;
    int*   cursor = (int*)ws; ws += N_NODES;
    int*   sE     = (int*)ws; ws += N_EDGES;
    int*   attr   = (int*)ws; ws += N_EDGES;
    int*   gE     = (int*)ws; ws += N_EDGES;
    int*   cnt    = (int*)ws; ws += 4;
    int*   lists  = (int*)ws; ws += (size_t)TT * N_NODES;

    const int nodeBlocksX = (N_NODES + NPB - 1) / NPB;  // 3125
    dim3 nodeGrid(nodeBlocksX, TT);
    dim3 qrelGrid(nodeBlocksX, RR);
    const int eB = (N_EDGES + 255) / 256;               // 1954
    const int edgeBlocks = (N_EDGES * HH + 255) / 256;  // 15625

    // type bins + CSR build (inputs constant; rebuilt each call for capture safety)
    hipMemsetAsync(cnt, 0, 4 * sizeof(int), stream);
    hipMemsetAsync(deg, 0, N_NODES * sizeof(int), stream);
    k_bin<<<(N_NODES + 255) / 256, 256, 0, stream>>>(node_type, cnt, lists);
    k_deg<<<eB, 256, 0, stream>>>(tgt, deg);
    k_scan<<<1, 1024, 0, stream>>>(deg, rowptr);
    hipMemcpyAsync(cursor, rowptr, N_NODES * sizeof(int),
                   hipMemcpyDeviceToDevice, stream);
    k_fill<<<eB, 256, 0, stream>>>(src, tgt, edge_type, edge_time, node_type,
                                   cursor, sE, attr, gE);

    k_sin_table<<<(MAXT_ * 64 + 255) / 256, 256, 0, stream>>>(tab);
    k_adapter<<<nodeGrid, 128, 0, stream>>>(node_feature, cnt, lists, adapt_W, adapt_b, hA);

    for (int l = 0; l < NLAYER; ++l) {
        const float* hin = (l == 0) ? hA : hB;
        float* hout = (l == 0) ? hB : (float*)d_out;
        const float* kW_l = kW + (size_t)l * TT * NHID * NHID;
        const float* kb_l = kb + (size_t)l * TT * NHID;
        const float* qW_l = qW + (size_t)l * TT * NHID * NHID;
        const float* qb_l = qb + (size_t)l * TT * NHID;
        const float* vW_l = vW + (size_t)l * TT * NHID * NHID;
        const float* vb_l = vb + (size_t)l * TT * NHID;
        const float* aW_l = aW + (size_t)l * TT * NHID * NHID;
        const float* ab_l = ab + (size_t)l * TT * NHID;
        const float* ratt_l = rel_att + (size_t)l * RR * HH * DKH * DKH;
        const float* rmsg_l = rel_msg + (size_t)l * RR * HH * DKH * DKH;
        const float* rpri_l = rel_pri + (size_t)l * RR * HH;
        const float* skip_l = skip + (size_t)l * TT;
        const float* rteW_l = rteW + (size_t)l * NHID * NHID;
        const float* rteb_l = rteb + (size_t)l * NHID;

        k_rte_proj<<<MAXT_, 128, 0, stream>>>(tab, rteW_l, rteb_l, proj);
        dim3 rkvGrid(MAXT_, TT);
        k_rkv<<<rkvGrid, 128, 0, stream>>>(proj, kW_l, vW_l, RK16, RV);
        k_node_lin<<<nodeGrid, 128, 0, stream>>>(hin, cnt, lists,
                                                 kW_l, kb_l, qW_l, qb_l, vW_l, vb_l,
                                                 hk16, q16, hv16);
        k_qrel<<<qrelGrid, 128, 0, stream>>>(q16, ratt_l, u316);
        k_att<<<edgeBlocks, 256, 0, stream>>>(hk16, u316, RK16, sE, attr, gE,
                                              rpri_l, att2);
        k_csr<<<N_NODES, 128, 0, stream>>>(hv16, RV, att2, rowptr, sE, attr,
                                           rmsg_l, agg);
        k_out<<<nodeGrid, 128, 0, stream>>>(agg, hin, cnt, lists, aW_l, ab_l, skip_l, hout);
    }
}

// Round 10
// 1028.429 us; speedup vs baseline: 1.1177x; 1.1177x over previous
//
#include <hip/hip_runtime.h>
#include <hip/hip_fp16.h>
#include <float.h>
#include <math.h>

#define N_NODES 50000
#define N_EDGES 500000
#define TT 3
#define RR 4
#define HH 8
#define NHID 128
#define NLAYER 2
#define DIN_ 166
#define MAXT_ 240
#define DKH 16
#define NPB 16
#define NPB2 32

// -------------------- setup kernels --------------------

__global__ void k_sin_table(float* __restrict__ tab) {
    int idx = blockIdx.x * blockDim.x + threadIdx.x;
    if (idx >= MAXT_ * 64) return;
    int p = idx / 64, i2 = idx % 64;
    const double c = -9.210340371976184 / 128.0;   // -ln(10000)/NH
    double div = exp((double)(2 * i2) * c);
    double a = (double)p * div;
    const double s128 = 0.08838834764831845;       // 1/sqrt(128)
    tab[p * NHID + 2 * i2]     = (float)(sin(a) * s128);
    tab[p * NHID + 2 * i2 + 1] = (float)(cos(a) * s128);
}

__global__ void k_bin(const int* __restrict__ ntype, int* __restrict__ cnt,
                      int* __restrict__ lists) {
    int n = blockIdx.x * 256 + threadIdx.x;
    int t = (n < N_NODES) ? ntype[n] : -1;
    int lane = threadIdx.x & 63;
    #pragma unroll
    for (int tt = 0; tt < TT; ++tt) {
        unsigned long long mask = __ballot(t == tt);
        if (mask) {
            int leader = (int)__ffsll(mask) - 1;
            int base = 0;
            if (lane == leader) base = atomicAdd(&cnt[tt], __popcll(mask));
            base = __shfl(base, leader);
            if (t == tt) {
                int rank = __popcll(mask & ((1ULL << lane) - 1ULL));
                lists[tt * N_NODES + base + rank] = n;
            }
        }
    }
}

// -------------------- CSR build --------------------

__global__ void k_deg(const int* __restrict__ tgt, int* __restrict__ deg) {
    int e = blockIdx.x * 256 + threadIdx.x;
    if (e < N_EDGES) atomicAdd(&deg[tgt[e]], 1);
}

__global__ void k_scan(const int* __restrict__ deg, int* __restrict__ rowptr) {
    __shared__ int wsum[16];
    __shared__ int carry_s;
    int tid = threadIdx.x;           // 1024
    int lane = tid & 63, wid = tid >> 6;
    if (tid == 0) { carry_s = 0; rowptr[0] = 0; }
    __syncthreads();
    for (int base = 0; base < N_NODES; base += 1024) {
        int idx = base + tid;
        int x = (idx < N_NODES) ? deg[idx] : 0;
        #pragma unroll
        for (int off = 1; off < 64; off <<= 1) {
            int y = __shfl_up(x, off, 64);
            if (lane >= off) x += y;
        }
        if (lane == 63) wsum[wid] = x;
        __syncthreads();
        if (wid == 0) {
            int w = (lane < 16) ? wsum[lane] : 0;
            #pragma unroll
            for (int off = 1; off < 16; off <<= 1) {
                int y = __shfl_up(w, off, 64);
                if (lane >= off) w += y;
            }
            if (lane < 16) wsum[lane] = w;
        }
        __syncthreads();
        int waveoff = (wid > 0) ? wsum[wid - 1] : 0;
        int incl = carry_s + waveoff + x;
        if (idx < N_NODES) rowptr[idx + 1] = incl;
        __syncthreads();
        if (tid == 1023) carry_s = incl;
        __syncthreads();
    }
}

__global__ void k_fill(const int* __restrict__ src, const int* __restrict__ tgt,
                       const int* __restrict__ etype, const int* __restrict__ etime,
                       const int* __restrict__ ntype, int* __restrict__ cursor,
                       int* __restrict__ sE, int* __restrict__ attr,
                       int* __restrict__ gE) {
    int e = blockIdx.x * 256 + threadIdx.x;
    if (e >= N_EDGES) return;
    int g = tgt[e];
    int s = src[e];
    int r = etype[e];
    int tm = etime[e];
    int t = ntype[s];
    int p = atomicAdd(&cursor[g], 1);
    sE[p] = s;
    attr[p] = (r << 12) | (tm * TT + t);
    gE[p] = g;
}

// -------------------- node-level linears (type-binned) --------------------

__global__ void k_adapter(const float* __restrict__ x, const int* __restrict__ cnt,
                          const int* __restrict__ lists,
                          const float* __restrict__ W, const float* __restrict__ b,
                          float* __restrict__ h) {
    int t = blockIdx.y;
    int c = cnt[t];
    int i0 = blockIdx.x * NPB;
    if (i0 >= c) return;
    int j = threadIdx.x;
    __shared__ float xs[NPB][DIN_];
    __shared__ int nidx[NPB];
    if (j < NPB) nidx[j] = (i0 + j < c) ? lists[t * N_NODES + i0 + j] : -1;
    __syncthreads();
    int nr[NPB];
    #pragma unroll
    for (int m = 0; m < NPB; ++m) nr[m] = nidx[m];
    #pragma unroll
    for (int m = 0; m < NPB; ++m) {
        int n = nr[m];
        for (int d = j; d < DIN_; d += 128)
            xs[m][d] = (n >= 0) ? x[(size_t)n * DIN_ + d] : 0.f;
    }
    __syncthreads();
    const float* Wt = W + (size_t)t * DIN_ * NHID;
    float bj = b[t * NHID + j];
    float acc[NPB];
    #pragma unroll
    for (int m = 0; m < NPB; ++m) acc[m] = bj;
    for (int d = 0; d < DIN_; ++d) {
        float w = Wt[d * NHID + j];
        #pragma unroll
        for (int m = 0; m < NPB; ++m) acc[m] = fmaf(xs[m][d], w, acc[m]);
    }
    #pragma unroll
    for (int m = 0; m < NPB; ++m) {
        int n = nr[m];
        if (n >= 0) h[(size_t)n * NHID + j] = tanhf(acc[m]);
    }
}

// Fused: hk/hv (fp16 gather tables) + u3f = rel_att[r] @ q  (f32, exact chain).
// 32 nodes/block. Transposed LDS staging: per-i GEMM step = 8 x ds_read_b128
// broadcast + 96 FMA. qrel epilogue reuses the same LDS for aq (row-major).
__global__ __launch_bounds__(128) void k_node_lin(
        const float* __restrict__ h, const int* __restrict__ cnt,
        const int* __restrict__ lists,
        const float* __restrict__ Wk, const float* __restrict__ bk,
        const float* __restrict__ Wq, const float* __restrict__ bq,
        const float* __restrict__ Wv, const float* __restrict__ bv,
        const float* __restrict__ rel_att,
        __half* __restrict__ hk16, __half* __restrict__ hv16,
        float* __restrict__ u3f) {
    int t = blockIdx.y;
    int c = cnt[t];
    int i0 = blockIdx.x * NPB2;
    if (i0 >= c) return;
    int j = threadIdx.x;
    __shared__ int nidx[NPB2];
    __shared__ float hsT[NHID][36];   // 18.4 KB; rows 144 B (16B-aligned)
    float (*aqs)[132] = (float(*)[132])&hsT[0][0];   // 16.9 KB overlay

    if (j < NPB2) nidx[j] = (i0 + j < c) ? lists[t * N_NODES + i0 + j] : -1;
    __syncthreads();
    for (int m = 0; m < NPB2; ++m) {
        int n = nidx[m];
        hsT[j][m] = (n >= 0) ? h[(size_t)n * NHID + j] : 0.f;
    }
    __syncthreads();

    const float* WkT = Wk + (size_t)t * NHID * NHID;
    const float* WqT = Wq + (size_t)t * NHID * NHID;
    const float* WvT = Wv + (size_t)t * NHID * NHID;
    float ak[NPB2], aq[NPB2], av[NPB2];
    float bkj = bk[t * NHID + j], bqj = bq[t * NHID + j], bvj = bv[t * NHID + j];
    #pragma unroll
    for (int m = 0; m < NPB2; ++m) { ak[m] = bkj; aq[m] = bqj; av[m] = bvj; }
    for (int i = 0; i < NHID; ++i) {
        float wk = WkT[i * NHID + j];
        float wq = WqT[i * NHID + j];
        float wv = WvT[i * NHID + j];
        const float4* hrow = (const float4*)&hsT[i][0];
        #pragma unroll
        for (int cc = 0; cc < 8; ++cc) {
            float4 h4 = hrow[cc];
            int mb = cc * 4;
            ak[mb+0] = fmaf(h4.x, wk, ak[mb+0]);
            ak[mb+1] = fmaf(h4.y, wk, ak[mb+1]);
            ak[mb+2] = fmaf(h4.z, wk, ak[mb+2]);
            ak[mb+3] = fmaf(h4.w, wk, ak[mb+3]);
            aq[mb+0] = fmaf(h4.x, wq, aq[mb+0]);
            aq[mb+1] = fmaf(h4.y, wq, aq[mb+1]);
            aq[mb+2] = fmaf(h4.z, wq, aq[mb+2]);
            aq[mb+3] = fmaf(h4.w, wq, aq[mb+3]);
            av[mb+0] = fmaf(h4.x, wv, av[mb+0]);
            av[mb+1] = fmaf(h4.y, wv, av[mb+1]);
            av[mb+2] = fmaf(h4.z, wv, av[mb+2]);
            av[mb+3] = fmaf(h4.w, wv, av[mb+3]);
        }
    }
    #pragma unroll
    for (int m = 0; m < NPB2; ++m) {
        int n = nidx[m];
        if (n >= 0) {
            hk16[(size_t)n * NHID + j] = __float2half(ak[m]);
            hv16[(size_t)n * NHID + j] = __float2half(av[m]);
        }
    }
    __syncthreads();   // GEMM reads of hsT done; safe to overlay aqs
    for (int m = 0; m < NPB2; ++m) aqs[m][j] = aq[m];
    __syncthreads();

    // qrel: u3[n,r][h*16+f] = sum_x rel_att[r][h][f][x] * q[n][h*16+x]
    // (row f of A — the k_rel contraction is over A's SECOND index at fixed d=f)
    int hh = j >> 4, f = j & 15;
    float A[RR][DKH];
    #pragma unroll
    for (int r = 0; r < RR; ++r) {
        const float4* Arow = (const float4*)(rel_att + (((r * HH + hh) << 8) | (f * 16)));
        #pragma unroll
        for (int cc = 0; cc < 4; ++cc) {
            float4 a4 = Arow[cc];
            A[r][cc*4+0] = a4.x; A[r][cc*4+1] = a4.y;
            A[r][cc*4+2] = a4.z; A[r][cc*4+3] = a4.w;
        }
    }
    for (int m = 0; m < NPB2; ++m) {
        int n = nidx[m];
        if (n < 0) continue;
        const float4* arow = (const float4*)&aqs[m][hh * 16];
        float qv[DKH];
        #pragma unroll
        for (int cc = 0; cc < 4; ++cc) {
            float4 q4 = arow[cc];
            qv[cc*4+0] = q4.x; qv[cc*4+1] = q4.y;
            qv[cc*4+2] = q4.z; qv[cc*4+3] = q4.w;
        }
        #pragma unroll
        for (int r = 0; r < RR; ++r) {
            float u = 0.f;
            #pragma unroll
            for (int d = 0; d < DKH; ++d) u = fmaf(A[r][d], qv[d], u);
            u3f[((size_t)n * RR + r) * NHID + j] = u;
        }
    }
}

// trans = gelu(agg)@aW[t]+ab[t]; hout = trans*alpha + hin*(1-alpha)
// 32 nodes/block, transposed LDS staging (same scheme as k_node_lin).
__global__ __launch_bounds__(128) void k_out(
        const float* __restrict__ agg, const float* __restrict__ hin,
        const int* __restrict__ cnt, const int* __restrict__ lists,
        const float* __restrict__ aW, const float* __restrict__ ab,
        const float* __restrict__ skp, float* __restrict__ hout) {
    int t = blockIdx.y;
    int c = cnt[t];
    int i0 = blockIdx.x * NPB2;
    if (i0 >= c) return;
    int j = threadIdx.x;
    __shared__ int nidx[NPB2];
    __shared__ float gsT[NHID][36];
    if (j < NPB2) nidx[j] = (i0 + j < c) ? lists[t * N_NODES + i0 + j] : -1;
    __syncthreads();
    for (int m = 0; m < NPB2; ++m) {
        int n = nidx[m];
        float xv = (n >= 0) ? agg[(size_t)n * NHID + j] : 0.f;
        gsT[j][m] = 0.5f * xv * (1.f + erff(xv * 0.7071067811865476f));
    }
    __syncthreads();
    const float* Wt = aW + (size_t)t * NHID * NHID;
    float bj = ab[t * NHID + j];
    float acc[NPB2];
    #pragma unroll
    for (int m = 0; m < NPB2; ++m) acc[m] = bj;
    for (int i = 0; i < NHID; ++i) {
        float w = Wt[i * NHID + j];
        const float4* grow = (const float4*)&gsT[i][0];
        #pragma unroll
        for (int cc = 0; cc < 8; ++cc) {
            float4 g4 = grow[cc];
            int mb = cc * 4;
            acc[mb+0] = fmaf(g4.x, w, acc[mb+0]);
            acc[mb+1] = fmaf(g4.y, w, acc[mb+1]);
            acc[mb+2] = fmaf(g4.z, w, acc[mb+2]);
            acc[mb+3] = fmaf(g4.w, w, acc[mb+3]);
        }
    }
    float alpha = 1.f / (1.f + expf(-skp[t]));
    #pragma unroll
    for (int m = 0; m < NPB2; ++m) {
        int n = nidx[m];
        if (n >= 0)
            hout[(size_t)n * NHID + j] =
                acc[m] * alpha + hin[(size_t)n * NHID + j] * (1.f - alpha);
    }
}

// -------------------- tiny RTE projections --------------------

__global__ void k_rte_proj(const float* __restrict__ tab, const float* __restrict__ rteW,
                           const float* __restrict__ rteb, float* __restrict__ proj) {
    int p = blockIdx.x;
    int j = threadIdx.x;
    __shared__ float ts[NHID];
    ts[j] = tab[p * NHID + j];
    __syncthreads();
    float acc = rteb[j];
    for (int i = 0; i < NHID; ++i) acc = fmaf(ts[i], rteW[i * NHID + j], acc);
    proj[p * NHID + j] = acc;
}

__global__ void k_rkv(const float* __restrict__ proj, const float* __restrict__ kW,
                      const float* __restrict__ vW, __half* __restrict__ RK16,
                      float* __restrict__ RV) {
    int p = blockIdx.x, t = blockIdx.y;
    int j = threadIdx.x;
    __shared__ float ps[NHID];
    ps[j] = proj[p * NHID + j];
    __syncthreads();
    const float* Wk = kW + (size_t)t * NHID * NHID;
    const float* Wv = vW + (size_t)t * NHID * NHID;
    float ak = 0.f, av = 0.f;
    for (int i = 0; i < NHID; ++i) {
        float pi = ps[i];
        ak = fmaf(pi, Wk[i * NHID + j], ak);
        av = fmaf(pi, Wv[i * NHID + j], av);
    }
    RK16[((size_t)p * TT + t) * NHID + j] = __float2half(ak);
    RV[((size_t)p * TT + t) * NHID + j] = av;
}

// -------------------- edge pass 1: attention scores --------------------

// att[e,h] = ((hk[s]+RK[row]) . u3[g,r])[h] * pri / 4 — pure 16-dim dot.
__global__ __launch_bounds__(256) void k_att(
        const __half* __restrict__ hk16, const float* __restrict__ u3f,
        const __half* __restrict__ RK16,
        const int* __restrict__ sE, const int* __restrict__ attr,
        const int* __restrict__ gE,
        const float* __restrict__ rel_pri, float* __restrict__ att2) {
    int idx = blockIdx.x * 256 + threadIdx.x;
    if (idx >= N_EDGES * HH) return;
    int k = idx >> 3, h = idx & 7;
    int s = sE[k];
    int a = attr[k];
    int r = a >> 12, row = a & 4095;
    int g = gE[k];
    const __half2* hk2 = (const __half2*)hk16 + (size_t)s * 64 + h * 8;
    const __half2* rk2 = (const __half2*)RK16 + (size_t)row * 64 + h * 8;
    const float4* u4 = (const float4*)(u3f + ((size_t)g * RR + r) * NHID) + h * 4;
    float acc = 0.f;
    #pragma unroll
    for (int i2 = 0; i2 < 4; ++i2) {
        float4 u = u4[i2];
        float2 p0 = __half22float2(hk2[2 * i2]);
        float2 r0 = __half22float2(rk2[2 * i2]);
        float2 p1 = __half22float2(hk2[2 * i2 + 1]);
        float2 r1 = __half22float2(rk2[2 * i2 + 1]);
        acc = fmaf(p0.x + r0.x, u.x, acc);
        acc = fmaf(p0.y + r0.y, u.y, acc);
        acc = fmaf(p1.x + r1.x, u.z, acc);
        acc = fmaf(p1.y + r1.y, u.w, acc);
    }
    acc *= rel_pri[r * HH + h] * 0.25f;
    att2[(size_t)h * N_EDGES + k] = acc;
}

// -------------------- edge pass 2: CSR softmax + aggregate --------------------

__global__ __launch_bounds__(128) void k_csr(
        const __half* __restrict__ hv16, const float* __restrict__ RV,
        float* __restrict__ att2,
        const int* __restrict__ rowptr, const int* __restrict__ sE,
        const int* __restrict__ attr,
        const float* __restrict__ rel_msg, float* __restrict__ agg) {
    int n = blockIdx.x;
    int tid = threadIdx.x;
    int h = tid >> 4, f = tid & 15;
    int beg = rowptr[n], end = rowptr[n + 1];
    float* ap = att2 + (size_t)h * N_EDGES;

    float m = -FLT_MAX;
    for (int k = beg + f; k < end; k += 16) m = fmaxf(m, ap[k]);
    #pragma unroll
    for (int mask = 1; mask <= 8; mask <<= 1)
        m = fmaxf(m, __shfl_xor(m, mask, 64));

    float ssum = 0.f;
    for (int k = beg + f; k < end; k += 16) {
        float ex = expf(ap[k] - m);
        ap[k] = ex;
        ssum += ex;
    }
    #pragma unroll
    for (int mask = 1; mask <= 8; mask <<= 1)
        ssum += __shfl_xor(ssum, mask, 64);
    float rden = 1.f / fmaxf(ssum, 1e-9f);
    __syncthreads();

    float a0 = 0.f, a1 = 0.f, a2 = 0.f, a3 = 0.f;
    #pragma unroll 2
    for (int k = beg; k < end; ++k) {
        int s = sE[k];
        int a = attr[k];
        int r = a >> 12, row = a & 4095;
        float vvt = __half2float(hv16[(size_t)s * NHID + tid])
                    + RV[(size_t)row * NHID + tid];
        float wv = ap[k] * vvt;
        a0 += (r == 0) ? wv : 0.f;
        a1 += (r == 1) ? wv : 0.f;
        a2 += (r == 2) ? wv : 0.f;
        a3 += (r == 3) ? wv : 0.f;
    }

    int lanebase = tid & 48;
    float out = 0.f;
    #pragma unroll
    for (int r = 0; r < RR; ++r) {
        float ar = (r == 0) ? a0 : (r == 1) ? a1 : (r == 2) ? a2 : a3;
        const float* M = rel_msg + ((r * HH + h) << 8) + f;
        #pragma unroll
        for (int d = 0; d < DKH; ++d) {
            float vd = __shfl(ar, lanebase + d, 64);
            out = fmaf(vd, M[d * 16], out);
        }
    }
    agg[(size_t)n * NHID + tid] = out * rden;
}

// -------------------- launch --------------------

extern "C" void kernel_launch(void* const* d_in, const int* in_sizes, int n_in,
                              void* d_out, int out_size, void* d_ws, size_t ws_size,
                              hipStream_t stream) {
    const float* node_feature = (const float*)d_in[0];
    const int*   node_type    = (const int*)d_in[1];
    const int*   edge_time    = (const int*)d_in[2];
    const int*   edge_index   = (const int*)d_in[3];
    const int*   edge_type    = (const int*)d_in[4];
    const float* adapt_W = (const float*)d_in[5];
    const float* adapt_b = (const float*)d_in[6];
    const float* kW = (const float*)d_in[7];
    const float* kb = (const float*)d_in[8];
    const float* qW = (const float*)d_in[9];
    const float* qb = (const float*)d_in[10];
    const float* vW = (const float*)d_in[11];
    const float* vb = (const float*)d_in[12];
    const float* aW = (const float*)d_in[13];
    const float* ab = (const float*)d_in[14];
    const float* rel_att = (const float*)d_in[15];
    const float* rel_msg = (const float*)d_in[16];
    const float* rel_pri = (const float*)d_in[17];
    const float* skip = (const float*)d_in[18];
    const float* rteW = (const float*)d_in[19];
    const float* rteb = (const float*)d_in[20];

    const int* src = edge_index;             // edge_index[0][:]
    const int* tgt = edge_index + N_EDGES;   // edge_index[1][:]

    float* ws = (float*)d_ws;
    float* hA   = ws; ws += (size_t)N_NODES * NHID;
    float* agg  = ws; ws += (size_t)N_NODES * NHID;
    float* att2 = ws; ws += (size_t)N_EDGES * HH;
    float* u3f  = ws; ws += (size_t)N_NODES * RR * NHID;
    float* tab  = ws; ws += MAXT_ * NHID;
    float* proj = ws; ws += MAXT_ * NHID;
    float* RV   = ws; ws += MAXT_ * TT * NHID;
    __half* hk16 = (__half*)ws; ws += (size_t)N_NODES * NHID / 2;
    __half* hv16 = (__half*)ws; ws += (size_t)N_NODES * NHID / 2;
    __half* RK16 = (__half*)ws; ws += (size_t)MAXT_ * TT * NHID / 2;
    int*   deg    = (int*)ws; ws += N_NODES;
    int*   rowptr = (int*)ws; ws += N_NODES + 1;
    int*   cursor = (int*)ws; ws += N_NODES;
    int*   sE     = (int*)ws; ws += N_EDGES;
    int*   attr   = (int*)ws; ws += N_EDGES;
    int*   gE     = (int*)ws; ws += N_EDGES;
    int*   cnt    = (int*)ws; ws += 4;
    int*   lists  = (int*)ws; ws += (size_t)TT * N_NODES;

    const int nodeBlocksX = (N_NODES + NPB - 1) / NPB;     // 3125
    const int nodeBlocksX2 = (N_NODES + NPB2 - 1) / NPB2;  // 1563
    dim3 nodeGrid(nodeBlocksX, TT);
    dim3 nodeGrid2(nodeBlocksX2, TT);
    const int eB = (N_EDGES + 255) / 256;                  // 1954
    const int edgeBlocks = (N_EDGES * HH + 255) / 256;     // 15625

    hipMemsetAsync(cnt, 0, 4 * sizeof(int), stream);
    hipMemsetAsync(deg, 0, N_NODES * sizeof(int), stream);
    k_bin<<<(N_NODES + 255) / 256, 256, 0, stream>>>(node_type, cnt, lists);
    k_deg<<<eB, 256, 0, stream>>>(tgt, deg);
    k_scan<<<1, 1024, 0, stream>>>(deg, rowptr);
    hipMemcpyAsync(cursor, rowptr, N_NODES * sizeof(int),
                   hipMemcpyDeviceToDevice, stream);
    k_fill<<<eB, 256, 0, stream>>>(src, tgt, edge_type, edge_time, node_type,
                                   cursor, sE, attr, gE);

    k_sin_table<<<(MAXT_ * 64 + 255) / 256, 256, 0, stream>>>(tab);
    k_adapter<<<nodeGrid, 128, 0, stream>>>(node_feature, cnt, lists, adapt_W, adapt_b, hA);

    for (int l = 0; l < NLAYER; ++l) {
        const float* hin = hA;
        float* hout = (l == 0) ? hA : (float*)d_out;   // layer 0 in-place (safe: per-thread R-then-W)
        const float* kW_l = kW + (size_t)l * TT * NHID * NHID;
        const float* kb_l = kb + (size_t)l * TT * NHID;
        const float* qW_l = qW + (size_t)l * TT * NHID * NHID;
        const float* qb_l = qb + (size_t)l * TT * NHID;
        const float* vW_l = vW + (size_t)l * TT * NHID * NHID;
        const float* vb_l = vb + (size_t)l * TT * NHID;
        const float* aW_l = aW + (size_t)l * TT * NHID * NHID;
        const float* ab_l = ab + (size_t)l * TT * NHID;
        const float* ratt_l = rel_att + (size_t)l * RR * HH * DKH * DKH;
        const float* rmsg_l = rel_msg + (size_t)l * RR * HH * DKH * DKH;
        const float* rpri_l = rel_pri + (size_t)l * RR * HH;
        const float* skip_l = skip + (size_t)l * TT;
        const float* rteW_l = rteW + (size_t)l * NHID * NHID;
        const float* rteb_l = rteb + (size_t)l * NHID;

        k_rte_proj<<<MAXT_, 128, 0, stream>>>(tab, rteW_l, rteb_l, proj);
        dim3 rkvGrid(MAXT_, TT);
        k_rkv<<<rkvGrid, 128, 0, stream>>>(proj, kW_l, vW_l, RK16, RV);
        k_node_lin<<<nodeGrid2, 128, 0, stream>>>(hin, cnt, lists,
                                                  kW_l, kb_l, qW_l, qb_l, vW_l, vb_l,
                                                  ratt_l, hk16, hv16, u3f);
        k_att<<<edgeBlocks, 256, 0, stream>>>(hk16, u3f, RK16, sE, attr, gE,
                                              rpri_l, att2);
        k_csr<<<N_NODES, 128, 0, stream>>>(hv16, RV, att2, rowptr, sE, attr,
                                           rmsg_l, agg);
        k_out<<<nodeGrid2, 128, 0, stream>>>(agg, hin, cnt, lists, aW_l, ab_l,
                                             skip_l, hout);
    }
}

// Round 11
// 920.860 us; speedup vs baseline: 1.2483x; 1.1168x over previous
//
#include <hip/hip_runtime.h>
#include <hip/hip_fp16.h>
#include <float.h>
#include <math.h>

#define N_NODES 50000
#define N_EDGES 500000
#define TT 3
#define RR 4
#define HH 8
#define NHID 128
#define NLAYER 2
#define DIN_ 166
#define MAXT_ 240
#define DKH 16
#define NPB 16
#define NPB2 32

// -------------------- setup kernels --------------------

__global__ void k_sin_table(float* __restrict__ tab) {
    int idx = blockIdx.x * blockDim.x + threadIdx.x;
    if (idx >= MAXT_ * 64) return;
    int p = idx / 64, i2 = idx % 64;
    const double c = -9.210340371976184 / 128.0;   // -ln(10000)/NH
    double div = exp((double)(2 * i2) * c);
    double a = (double)p * div;
    const double s128 = 0.08838834764831845;       // 1/sqrt(128)
    tab[p * NHID + 2 * i2]     = (float)(sin(a) * s128);
    tab[p * NHID + 2 * i2 + 1] = (float)(cos(a) * s128);
}

__global__ void k_bin(const int* __restrict__ ntype, int* __restrict__ cnt,
                      int* __restrict__ lists) {
    int n = blockIdx.x * 256 + threadIdx.x;
    int t = (n < N_NODES) ? ntype[n] : -1;
    int lane = threadIdx.x & 63;
    #pragma unroll
    for (int tt = 0; tt < TT; ++tt) {
        unsigned long long mask = __ballot(t == tt);
        if (mask) {
            int leader = (int)__ffsll(mask) - 1;
            int base = 0;
            if (lane == leader) base = atomicAdd(&cnt[tt], __popcll(mask));
            base = __shfl(base, leader);
            if (t == tt) {
                int rank = __popcll(mask & ((1ULL << lane) - 1ULL));
                lists[tt * N_NODES + base + rank] = n;
            }
        }
    }
}

// -------------------- CSR build --------------------

__global__ void k_deg(const int* __restrict__ tgt, int* __restrict__ deg) {
    int e = blockIdx.x * 256 + threadIdx.x;
    if (e < N_EDGES) atomicAdd(&deg[tgt[e]], 1);
}

// hierarchical scan: block-local inclusive + block sums
__global__ void k_scan1(const int* __restrict__ deg, int* __restrict__ rowptr,
                        int* __restrict__ bsum) {
    int b = blockIdx.x, t = threadIdx.x;
    int idx = b * 256 + t;
    int x = (idx < N_NODES) ? deg[idx] : 0;
    int lane = t & 63, wid = t >> 6;
    __shared__ int wsum[4];
    #pragma unroll
    for (int off = 1; off < 64; off <<= 1) {
        int y = __shfl_up(x, off, 64);
        if (lane >= off) x += y;
    }
    if (lane == 63) wsum[wid] = x;
    __syncthreads();
    if (t == 0) {
        int acc = 0;
        #pragma unroll
        for (int i = 0; i < 4; ++i) { int v = wsum[i]; wsum[i] = acc; acc += v; }
        bsum[b] = acc;
    }
    __syncthreads();
    x += wsum[wid];
    if (idx < N_NODES) rowptr[idx + 1] = x;
}

// exclusive scan of block sums (nb <= 256)
__global__ void k_scan2(int* __restrict__ bsum, int nb) {
    int t = threadIdx.x;
    int orig = (t < nb) ? bsum[t] : 0;
    int x = orig;
    int lane = t & 63, wid = t >> 6;
    __shared__ int wsum[4];
    #pragma unroll
    for (int off = 1; off < 64; off <<= 1) {
        int y = __shfl_up(x, off, 64);
        if (lane >= off) x += y;
    }
    if (lane == 63) wsum[wid] = x;
    __syncthreads();
    if (t == 0) {
        int acc = 0;
        #pragma unroll
        for (int i = 0; i < 4; ++i) { int v = wsum[i]; wsum[i] = acc; acc += v; }
    }
    __syncthreads();
    x += wsum[wid];
    if (t < nb) bsum[t] = x - orig;
}

__global__ void k_scan3(int* __restrict__ rowptr, const int* __restrict__ bsum) {
    int b = blockIdx.x, t = threadIdx.x;
    int idx = b * 256 + t;
    if (idx < N_NODES) rowptr[idx + 1] += bsum[b];
    if (idx == 0) rowptr[0] = 0;
}

__global__ void k_fill(const int* __restrict__ src, const int* __restrict__ tgt,
                       const int* __restrict__ etype, const int* __restrict__ etime,
                       const int* __restrict__ ntype, int* __restrict__ cursor,
                       int* __restrict__ sE, int* __restrict__ attr,
                       int* __restrict__ gE) {
    int e = blockIdx.x * 256 + threadIdx.x;
    if (e >= N_EDGES) return;
    int g = tgt[e];
    int s = src[e];
    int r = etype[e];
    int tm = etime[e];
    int t = ntype[s];
    int p = atomicAdd(&cursor[g], 1);
    sE[p] = s;
    attr[p] = (r << 12) | (tm * TT + t);
    gE[p] = g;
}

// -------------------- node-level linears (type-binned) --------------------

__global__ void k_adapter(const float* __restrict__ x, const int* __restrict__ cnt,
                          const int* __restrict__ lists,
                          const float* __restrict__ W, const float* __restrict__ b,
                          float* __restrict__ h) {
    int t = blockIdx.y;
    int c = cnt[t];
    int i0 = blockIdx.x * NPB;
    if (i0 >= c) return;
    int j = threadIdx.x;
    __shared__ float xs[NPB][DIN_];
    __shared__ int nidx[NPB];
    if (j < NPB) nidx[j] = (i0 + j < c) ? lists[t * N_NODES + i0 + j] : -1;
    __syncthreads();
    int nr[NPB];
    #pragma unroll
    for (int m = 0; m < NPB; ++m) nr[m] = nidx[m];
    #pragma unroll
    for (int m = 0; m < NPB; ++m) {
        int n = nr[m];
        for (int d = j; d < DIN_; d += 128)
            xs[m][d] = (n >= 0) ? x[(size_t)n * DIN_ + d] : 0.f;
    }
    __syncthreads();
    const float* Wt = W + (size_t)t * DIN_ * NHID;
    float bj = b[t * NHID + j];
    float acc[NPB];
    #pragma unroll
    for (int m = 0; m < NPB; ++m) acc[m] = bj;
    for (int d = 0; d < DIN_; ++d) {
        float w = Wt[d * NHID + j];
        #pragma unroll
        for (int m = 0; m < NPB; ++m) acc[m] = fmaf(xs[m][d], w, acc[m]);
    }
    #pragma unroll
    for (int m = 0; m < NPB; ++m) {
        int n = nr[m];
        if (n >= 0) h[(size_t)n * NHID + j] = tanhf(acc[m]);
    }
}

// Fused: hk/hv (fp16 gather tables) + u3f = rel_att[r] @ q  (f32 exact chain).
__global__ __launch_bounds__(128) void k_node_lin(
        const float* __restrict__ h, const int* __restrict__ cnt,
        const int* __restrict__ lists,
        const float* __restrict__ Wk, const float* __restrict__ bk,
        const float* __restrict__ Wq, const float* __restrict__ bq,
        const float* __restrict__ Wv, const float* __restrict__ bv,
        const float* __restrict__ rel_att,
        __half* __restrict__ hk16, __half* __restrict__ hv16,
        float* __restrict__ u3f) {
    int t = blockIdx.y;
    int c = cnt[t];
    int i0 = blockIdx.x * NPB2;
    if (i0 >= c) return;
    int j = threadIdx.x;
    __shared__ int nidx[NPB2];
    __shared__ float hsT[NHID][36];   // rows 144 B (16B-aligned)
    float (*aqs)[132] = (float(*)[132])&hsT[0][0];

    if (j < NPB2) nidx[j] = (i0 + j < c) ? lists[t * N_NODES + i0 + j] : -1;
    __syncthreads();
    for (int m = 0; m < NPB2; ++m) {
        int n = nidx[m];
        hsT[j][m] = (n >= 0) ? h[(size_t)n * NHID + j] : 0.f;
    }
    __syncthreads();

    const float* WkT = Wk + (size_t)t * NHID * NHID;
    const float* WqT = Wq + (size_t)t * NHID * NHID;
    const float* WvT = Wv + (size_t)t * NHID * NHID;
    float ak[NPB2], aq[NPB2], av[NPB2];
    float bkj = bk[t * NHID + j], bqj = bq[t * NHID + j], bvj = bv[t * NHID + j];
    #pragma unroll
    for (int m = 0; m < NPB2; ++m) { ak[m] = bkj; aq[m] = bqj; av[m] = bvj; }
    for (int i = 0; i < NHID; ++i) {
        float wk = WkT[i * NHID + j];
        float wq = WqT[i * NHID + j];
        float wv = WvT[i * NHID + j];
        const float4* hrow = (const float4*)&hsT[i][0];
        #pragma unroll
        for (int cc = 0; cc < 8; ++cc) {
            float4 h4 = hrow[cc];
            int mb = cc * 4;
            ak[mb+0] = fmaf(h4.x, wk, ak[mb+0]);
            ak[mb+1] = fmaf(h4.y, wk, ak[mb+1]);
            ak[mb+2] = fmaf(h4.z, wk, ak[mb+2]);
            ak[mb+3] = fmaf(h4.w, wk, ak[mb+3]);
            aq[mb+0] = fmaf(h4.x, wq, aq[mb+0]);
            aq[mb+1] = fmaf(h4.y, wq, aq[mb+1]);
            aq[mb+2] = fmaf(h4.z, wq, aq[mb+2]);
            aq[mb+3] = fmaf(h4.w, wq, aq[mb+3]);
            av[mb+0] = fmaf(h4.x, wv, av[mb+0]);
            av[mb+1] = fmaf(h4.y, wv, av[mb+1]);
            av[mb+2] = fmaf(h4.z, wv, av[mb+2]);
            av[mb+3] = fmaf(h4.w, wv, av[mb+3]);
        }
    }
    #pragma unroll
    for (int m = 0; m < NPB2; ++m) {
        int n = nidx[m];
        if (n >= 0) {
            hk16[(size_t)n * NHID + j] = __float2half(ak[m]);
            hv16[(size_t)n * NHID + j] = __float2half(av[m]);
        }
    }
    __syncthreads();
    for (int m = 0; m < NPB2; ++m) aqs[m][j] = aq[m];
    __syncthreads();

    // qrel: u3[n,r][h*16+f] = sum_x rel_att[r][h][f][x] * q[n][h*16+x]
    int hh = j >> 4, f = j & 15;
    float A[RR][DKH];
    #pragma unroll
    for (int r = 0; r < RR; ++r) {
        const float4* Arow = (const float4*)(rel_att + (((r * HH + hh) << 8) | (f * 16)));
        #pragma unroll
        for (int cc = 0; cc < 4; ++cc) {
            float4 a4 = Arow[cc];
            A[r][cc*4+0] = a4.x; A[r][cc*4+1] = a4.y;
            A[r][cc*4+2] = a4.z; A[r][cc*4+3] = a4.w;
        }
    }
    for (int m = 0; m < NPB2; ++m) {
        int n = nidx[m];
        if (n < 0) continue;
        const float4* arow = (const float4*)&aqs[m][hh * 16];
        float qv[DKH];
        #pragma unroll
        for (int cc = 0; cc < 4; ++cc) {
            float4 q4 = arow[cc];
            qv[cc*4+0] = q4.x; qv[cc*4+1] = q4.y;
            qv[cc*4+2] = q4.z; qv[cc*4+3] = q4.w;
        }
        #pragma unroll
        for (int r = 0; r < RR; ++r) {
            float u = 0.f;
            #pragma unroll
            for (int d = 0; d < DKH; ++d) u = fmaf(A[r][d], qv[d], u);
            u3f[((size_t)n * RR + r) * NHID + j] = u;
        }
    }
}

__global__ __launch_bounds__(128) void k_out(
        const __half* __restrict__ agg16, const float* __restrict__ hin,
        const int* __restrict__ cnt, const int* __restrict__ lists,
        const float* __restrict__ aW, const float* __restrict__ ab,
        const float* __restrict__ skp, float* __restrict__ hout) {
    int t = blockIdx.y;
    int c = cnt[t];
    int i0 = blockIdx.x * NPB2;
    if (i0 >= c) return;
    int j = threadIdx.x;
    __shared__ int nidx[NPB2];
    __shared__ float gsT[NHID][36];
    if (j < NPB2) nidx[j] = (i0 + j < c) ? lists[t * N_NODES + i0 + j] : -1;
    __syncthreads();
    for (int m = 0; m < NPB2; ++m) {
        int n = nidx[m];
        float xv = (n >= 0) ? __half2float(agg16[(size_t)n * NHID + j]) : 0.f;
        gsT[j][m] = 0.5f * xv * (1.f + erff(xv * 0.7071067811865476f));
    }
    __syncthreads();
    const float* Wt = aW + (size_t)t * NHID * NHID;
    float bj = ab[t * NHID + j];
    float acc[NPB2];
    #pragma unroll
    for (int m = 0; m < NPB2; ++m) acc[m] = bj;
    for (int i = 0; i < NHID; ++i) {
        float w = Wt[i * NHID + j];
        const float4* grow = (const float4*)&gsT[i][0];
        #pragma unroll
        for (int cc = 0; cc < 8; ++cc) {
            float4 g4 = grow[cc];
            int mb = cc * 4;
            acc[mb+0] = fmaf(g4.x, w, acc[mb+0]);
            acc[mb+1] = fmaf(g4.y, w, acc[mb+1]);
            acc[mb+2] = fmaf(g4.z, w, acc[mb+2]);
            acc[mb+3] = fmaf(g4.w, w, acc[mb+3]);
        }
    }
    float alpha = 1.f / (1.f + expf(-skp[t]));
    #pragma unroll
    for (int m = 0; m < NPB2; ++m) {
        int n = nidx[m];
        if (n >= 0)
            hout[(size_t)n * NHID + j] =
                acc[m] * alpha + hin[(size_t)n * NHID + j] * (1.f - alpha);
    }
}

// -------------------- RTE projection (proj fused in) --------------------

__global__ void k_rkv(const float* __restrict__ tab, const float* __restrict__ rteW,
                      const float* __restrict__ rteb,
                      const float* __restrict__ kW, const float* __restrict__ vW,
                      __half* __restrict__ RK16, float* __restrict__ RV) {
    int p = blockIdx.x, t = blockIdx.y;
    int j = threadIdx.x;
    __shared__ float ts[NHID];
    __shared__ float ps[NHID];
    ts[j] = tab[p * NHID + j];
    __syncthreads();
    float pj = rteb[j];
    for (int i = 0; i < NHID; ++i) pj = fmaf(ts[i], rteW[i * NHID + j], pj);
    ps[j] = pj;
    __syncthreads();
    const float* Wk = kW + (size_t)t * NHID * NHID;
    const float* Wv = vW + (size_t)t * NHID * NHID;
    float ak = 0.f, av = 0.f;
    for (int i = 0; i < NHID; ++i) {
        float pi = ps[i];
        ak = fmaf(pi, Wk[i * NHID + j], ak);
        av = fmaf(pi, Wv[i * NHID + j], av);
    }
    RK16[((size_t)p * TT + t) * NHID + j] = __float2half(ak);
    RV[((size_t)p * TT + t) * NHID + j] = av;
}

// -------------------- edge pass 1: attention scores (2 edges/thread) -------

__global__ __launch_bounds__(256) void k_att(
        const __half* __restrict__ hk16, const float* __restrict__ u3f,
        const __half* __restrict__ RK16,
        const int* __restrict__ sE, const int* __restrict__ attr,
        const int* __restrict__ gE,
        const float* __restrict__ rel_pri, float* __restrict__ att2) {
    int idx = blockIdx.x * 256 + threadIdx.x;
    if (idx >= (N_EDGES / 2) * HH) return;
    int p = idx >> 3, h = idx & 7;
    int k0 = p * 2;
    int2 ss = *(const int2*)(sE + k0);
    int2 aa = *(const int2*)(attr + k0);
    int2 gg = *(const int2*)(gE + k0);
    int r0 = aa.x >> 12, row0 = aa.x & 4095;
    int r1 = aa.y >> 12, row1 = aa.y & 4095;
    const __half2* hkA = (const __half2*)hk16 + (size_t)ss.x * 64 + h * 8;
    const __half2* rkA = (const __half2*)RK16 + (size_t)row0 * 64 + h * 8;
    const float4*  uA  = (const float4*)(u3f + ((size_t)gg.x * RR + r0) * NHID) + h * 4;
    const __half2* hkB = (const __half2*)hk16 + (size_t)ss.y * 64 + h * 8;
    const __half2* rkB = (const __half2*)RK16 + (size_t)row1 * 64 + h * 8;
    const float4*  uB  = (const float4*)(u3f + ((size_t)gg.y * RR + r1) * NHID) + h * 4;
    float accA = 0.f, accB = 0.f;
    #pragma unroll
    for (int i2 = 0; i2 < 4; ++i2) {
        float4 ua = uA[i2];
        float2 pa0 = __half22float2(hkA[2*i2]);
        float2 ra0 = __half22float2(rkA[2*i2]);
        float2 pa1 = __half22float2(hkA[2*i2+1]);
        float2 ra1 = __half22float2(rkA[2*i2+1]);
        accA = fmaf(pa0.x + ra0.x, ua.x, accA);
        accA = fmaf(pa0.y + ra0.y, ua.y, accA);
        accA = fmaf(pa1.x + ra1.x, ua.z, accA);
        accA = fmaf(pa1.y + ra1.y, ua.w, accA);
        float4 ub = uB[i2];
        float2 pb0 = __half22float2(hkB[2*i2]);
        float2 rb0 = __half22float2(rkB[2*i2]);
        float2 pb1 = __half22float2(hkB[2*i2+1]);
        float2 rb1 = __half22float2(rkB[2*i2+1]);
        accB = fmaf(pb0.x + rb0.x, ub.x, accB);
        accB = fmaf(pb0.y + rb0.y, ub.y, accB);
        accB = fmaf(pb1.x + rb1.x, ub.z, accB);
        accB = fmaf(pb1.y + rb1.y, ub.w, accB);
    }
    accA *= rel_pri[r0 * HH + h] * 0.25f;
    accB *= rel_pri[r1 * HH + h] * 0.25f;
    *(float2*)(att2 + (size_t)h * N_EDGES + k0) = make_float2(accA, accB);
}

// -------------------- edge pass 2: CSR softmax + aggregate (4-wide ILP) ----

__global__ __launch_bounds__(128) void k_csr(
        const __half* __restrict__ hv16, const float* __restrict__ RV,
        float* __restrict__ att2,
        const int* __restrict__ rowptr, const int* __restrict__ sE,
        const int* __restrict__ attr,
        const float* __restrict__ rel_msg, __half* __restrict__ agg16) {
    int n = blockIdx.x;
    int tid = threadIdx.x;
    int h = tid >> 4, f = tid & 15;
    int beg = rowptr[n], end = rowptr[n + 1];
    float* ap = att2 + (size_t)h * N_EDGES;

    float m = -FLT_MAX;
    for (int k = beg + f; k < end; k += 16) m = fmaxf(m, ap[k]);
    #pragma unroll
    for (int mask = 1; mask <= 8; mask <<= 1)
        m = fmaxf(m, __shfl_xor(m, mask, 64));

    float ssum = 0.f;
    for (int k = beg + f; k < end; k += 16) {
        float ex = expf(ap[k] - m);
        ap[k] = ex;
        ssum += ex;
    }
    #pragma unroll
    for (int mask = 1; mask <= 8; mask <<= 1)
        ssum += __shfl_xor(ssum, mask, 64);
    float rden = 1.f / fmaxf(ssum, 1e-9f);
    __syncthreads();

    // phase B with 4-wide explicit ILP on the gather chain
    float a0 = 0.f, a1 = 0.f, a2 = 0.f, a3 = 0.f;
    int k = beg;
    for (; k + 4 <= end; k += 4) {
        int s0 = sE[k],   s1 = sE[k+1], s2 = sE[k+2], s3 = sE[k+3];
        int t0 = attr[k], t1 = attr[k+1], t2 = attr[k+2], t3 = attr[k+3];
        float w0 = ap[k], w1 = ap[k+1], w2 = ap[k+2], w3 = ap[k+3];
        float v0 = __half2float(hv16[(size_t)s0 * NHID + tid]) + RV[(size_t)(t0 & 4095) * NHID + tid];
        float v1 = __half2float(hv16[(size_t)s1 * NHID + tid]) + RV[(size_t)(t1 & 4095) * NHID + tid];
        float v2 = __half2float(hv16[(size_t)s2 * NHID + tid]) + RV[(size_t)(t2 & 4095) * NHID + tid];
        float v3 = __half2float(hv16[(size_t)s3 * NHID + tid]) + RV[(size_t)(t3 & 4095) * NHID + tid];
        float wv0 = w0 * v0, wv1 = w1 * v1, wv2 = w2 * v2, wv3 = w3 * v3;
        int r0 = t0 >> 12, r1 = t1 >> 12, r2 = t2 >> 12, r3 = t3 >> 12;
        a0 += ((r0 == 0) ? wv0 : 0.f) + ((r1 == 0) ? wv1 : 0.f)
            + ((r2 == 0) ? wv2 : 0.f) + ((r3 == 0) ? wv3 : 0.f);
        a1 += ((r0 == 1) ? wv0 : 0.f) + ((r1 == 1) ? wv1 : 0.f)
            + ((r2 == 1) ? wv2 : 0.f) + ((r3 == 1) ? wv3 : 0.f);
        a2 += ((r0 == 2) ? wv0 : 0.f) + ((r1 == 2) ? wv1 : 0.f)
            + ((r2 == 2) ? wv2 : 0.f) + ((r3 == 2) ? wv3 : 0.f);
        a3 += ((r0 == 3) ? wv0 : 0.f) + ((r1 == 3) ? wv1 : 0.f)
            + ((r2 == 3) ? wv2 : 0.f) + ((r3 == 3) ? wv3 : 0.f);
    }
    for (; k < end; ++k) {
        int s = sE[k];
        int a = attr[k];
        float vvt = __half2float(hv16[(size_t)s * NHID + tid])
                    + RV[(size_t)(a & 4095) * NHID + tid];
        float wv = ap[k] * vvt;
        int r = a >> 12;
        a0 += (r == 0) ? wv : 0.f;
        a1 += (r == 1) ? wv : 0.f;
        a2 += (r == 2) ? wv : 0.f;
        a3 += (r == 3) ? wv : 0.f;
    }

    int lanebase = tid & 48;
    float out = 0.f;
    #pragma unroll
    for (int r = 0; r < RR; ++r) {
        float ar = (r == 0) ? a0 : (r == 1) ? a1 : (r == 2) ? a2 : a3;
        const float* M = rel_msg + ((r * HH + h) << 8) + f;
        #pragma unroll
        for (int d = 0; d < DKH; ++d) {
            float vd = __shfl(ar, lanebase + d, 64);
            out = fmaf(vd, M[d * 16], out);
        }
    }
    agg16[(size_t)n * NHID + tid] = __float2half(out * rden);
}

// -------------------- launch --------------------

extern "C" void kernel_launch(void* const* d_in, const int* in_sizes, int n_in,
                              void* d_out, int out_size, void* d_ws, size_t ws_size,
                              hipStream_t stream) {
    const float* node_feature = (const float*)d_in[0];
    const int*   node_type    = (const int*)d_in[1];
    const int*   edge_time    = (const int*)d_in[2];
    const int*   edge_index   = (const int*)d_in[3];
    const int*   edge_type    = (const int*)d_in[4];
    const float* adapt_W = (const float*)d_in[5];
    const float* adapt_b = (const float*)d_in[6];
    const float* kW = (const float*)d_in[7];
    const float* kb = (const float*)d_in[8];
    const float* qW = (const float*)d_in[9];
    const float* qb = (const float*)d_in[10];
    const float* vW = (const float*)d_in[11];
    const float* vb = (const float*)d_in[12];
    const float* aW = (const float*)d_in[13];
    const float* ab = (const float*)d_in[14];
    const float* rel_att = (const float*)d_in[15];
    const float* rel_msg = (const float*)d_in[16];
    const float* rel_pri = (const float*)d_in[17];
    const float* skip = (const float*)d_in[18];
    const float* rteW = (const float*)d_in[19];
    const float* rteb = (const float*)d_in[20];

    const int* src = edge_index;             // edge_index[0][:]
    const int* tgt = edge_index + N_EDGES;   // edge_index[1][:]

    float* ws = (float*)d_ws;
    float* hA   = ws; ws += (size_t)N_NODES * NHID;
    float* att2 = ws; ws += (size_t)N_EDGES * HH;
    float* u3f  = ws; ws += (size_t)N_NODES * RR * NHID;
    float* tab  = ws; ws += MAXT_ * NHID;
    float* RV   = ws; ws += MAXT_ * TT * NHID;
    __half* agg16 = (__half*)ws; ws += (size_t)N_NODES * NHID / 2;
    __half* hk16  = (__half*)ws; ws += (size_t)N_NODES * NHID / 2;
    __half* hv16  = (__half*)ws; ws += (size_t)N_NODES * NHID / 2;
    __half* RK16  = (__half*)ws; ws += (size_t)MAXT_ * TT * NHID / 2;
    int*   deg    = (int*)ws; ws += N_NODES;
    int*   rowptr = (int*)ws; ws += N_NODES + 2;   // +1 pad keeps 8B alignment below
    int*   cursor = (int*)ws; ws += N_NODES;
    int*   sE     = (int*)ws; ws += N_EDGES;
    int*   attr   = (int*)ws; ws += N_EDGES;
    int*   gE     = (int*)ws; ws += N_EDGES;
    int*   bsum   = (int*)ws; ws += 256;
    int*   cnt    = (int*)ws; ws += 4;
    int*   lists  = (int*)ws; ws += (size_t)TT * N_NODES;

    const int nodeBlocksX = (N_NODES + NPB - 1) / NPB;     // 3125
    const int nodeBlocksX2 = (N_NODES + NPB2 - 1) / NPB2;  // 1563
    dim3 nodeGrid(nodeBlocksX, TT);
    dim3 nodeGrid2(nodeBlocksX2, TT);
    const int eB = (N_EDGES + 255) / 256;                  // 1954
    const int attBlocks = ((N_EDGES / 2) * HH + 255) / 256;  // 7813
    const int scanBlocks = (N_NODES + 255) / 256;          // 196

    hipMemsetAsync(cnt, 0, 4 * sizeof(int), stream);
    hipMemsetAsync(deg, 0, N_NODES * sizeof(int), stream);
    k_bin<<<(N_NODES + 255) / 256, 256, 0, stream>>>(node_type, cnt, lists);
    k_deg<<<eB, 256, 0, stream>>>(tgt, deg);
    k_scan1<<<scanBlocks, 256, 0, stream>>>(deg, rowptr, bsum);
    k_scan2<<<1, 256, 0, stream>>>(bsum, scanBlocks);
    k_scan3<<<scanBlocks, 256, 0, stream>>>(rowptr, bsum);
    hipMemcpyAsync(cursor, rowptr, N_NODES * sizeof(int),
                   hipMemcpyDeviceToDevice, stream);
    k_fill<<<eB, 256, 0, stream>>>(src, tgt, edge_type, edge_time, node_type,
                                   cursor, sE, attr, gE);

    k_sin_table<<<(MAXT_ * 64 + 255) / 256, 256, 0, stream>>>(tab);
    k_adapter<<<nodeGrid, 128, 0, stream>>>(node_feature, cnt, lists, adapt_W, adapt_b, hA);

    for (int l = 0; l < NLAYER; ++l) {
        const float* hin = hA;
        float* hout = (l == 0) ? hA : (float*)d_out;   // layer 0 in-place (per-thread R-then-W)
        const float* kW_l = kW + (size_t)l * TT * NHID * NHID;
        const float* kb_l = kb + (size_t)l * TT * NHID;
        const float* qW_l = qW + (size_t)l * TT * NHID * NHID;
        const float* qb_l = qb + (size_t)l * TT * NHID;
        const float* vW_l = vW + (size_t)l * TT * NHID * NHID;
        const float* vb_l = vb + (size_t)l * TT * NHID;
        const float* aW_l = aW + (size_t)l * TT * NHID * NHID;
        const float* ab_l = ab + (size_t)l * TT * NHID;
        const float* ratt_l = rel_att + (size_t)l * RR * HH * DKH * DKH;
        const float* rmsg_l = rel_msg + (size_t)l * RR * HH * DKH * DKH;
        const float* rpri_l = rel_pri + (size_t)l * RR * HH;
        const float* skip_l = skip + (size_t)l * TT;
        const float* rteW_l = rteW + (size_t)l * NHID * NHID;
        const float* rteb_l = rteb + (size_t)l * NHID;

        dim3 rkvGrid(MAXT_, TT);
        k_rkv<<<rkvGrid, 128, 0, stream>>>(tab, rteW_l, rteb_l, kW_l, vW_l, RK16, RV);
        k_node_lin<<<nodeGrid2, 128, 0, stream>>>(hin, cnt, lists,
                                                  kW_l, kb_l, qW_l, qb_l, vW_l, vb_l,
                                                  ratt_l, hk16, hv16, u3f);
        k_att<<<attBlocks, 256, 0, stream>>>(hk16, u3f, RK16, sE, attr, gE,
                                             rpri_l, att2);
        k_csr<<<N_NODES, 128, 0, stream>>>(hv16, RV, att2, rowptr, sE, attr,
                                           rmsg_l, agg16);
        k_out<<<nodeGrid2, 128, 0, stream>>>(agg16, hin, cnt, lists, aW_l, ab_l,
                                             skip_l, hout);
    }
}

// Round 12
// 917.471 us; speedup vs baseline: 1.2529x; 1.0037x over previous
//
#include <hip/hip_runtime.h>
#include <hip/hip_fp16.h>
#include <float.h>
#include <math.h>

#define N_NODES 50000
#define N_EDGES 500000
#define TT 3
#define RR 4
#define HH 8
#define NHID 128
#define NLAYER 2
#define DIN_ 166
#define MAXT_ 240
#define DKH 16
#define NPB 16
#define NPB2 32

// -------------------- setup kernels --------------------

__global__ void k_sin_table(float* __restrict__ tab) {
    int idx = blockIdx.x * blockDim.x + threadIdx.x;
    if (idx >= MAXT_ * 64) return;
    int p = idx / 64, i2 = idx % 64;
    const double c = -9.210340371976184 / 128.0;   // -ln(10000)/NH
    double div = exp((double)(2 * i2) * c);
    double a = (double)p * div;
    const double s128 = 0.08838834764831845;       // 1/sqrt(128)
    tab[p * NHID + 2 * i2]     = (float)(sin(a) * s128);
    tab[p * NHID + 2 * i2 + 1] = (float)(cos(a) * s128);
}

__global__ void k_bin(const int* __restrict__ ntype, int* __restrict__ cnt,
                      int* __restrict__ lists) {
    int n = blockIdx.x * 256 + threadIdx.x;
    int t = (n < N_NODES) ? ntype[n] : -1;
    int lane = threadIdx.x & 63;
    #pragma unroll
    for (int tt = 0; tt < TT; ++tt) {
        unsigned long long mask = __ballot(t == tt);
        if (mask) {
            int leader = (int)__ffsll(mask) - 1;
            int base = 0;
            if (lane == leader) base = atomicAdd(&cnt[tt], __popcll(mask));
            base = __shfl(base, leader);
            if (t == tt) {
                int rank = __popcll(mask & ((1ULL << lane) - 1ULL));
                lists[tt * N_NODES + base + rank] = n;
            }
        }
    }
}

// -------------------- CSR build --------------------

__global__ void k_deg(const int* __restrict__ tgt, int* __restrict__ deg) {
    int e = blockIdx.x * 256 + threadIdx.x;
    if (e < N_EDGES) atomicAdd(&deg[tgt[e]], 1);
}

__global__ void k_scan1(const int* __restrict__ deg, int* __restrict__ rowptr,
                        int* __restrict__ bsum) {
    int b = blockIdx.x, t = threadIdx.x;
    int idx = b * 256 + t;
    int x = (idx < N_NODES) ? deg[idx] : 0;
    int lane = t & 63, wid = t >> 6;
    __shared__ int wsum[4];
    #pragma unroll
    for (int off = 1; off < 64; off <<= 1) {
        int y = __shfl_up(x, off, 64);
        if (lane >= off) x += y;
    }
    if (lane == 63) wsum[wid] = x;
    __syncthreads();
    if (t == 0) {
        int acc = 0;
        #pragma unroll
        for (int i = 0; i < 4; ++i) { int v = wsum[i]; wsum[i] = acc; acc += v; }
        bsum[b] = acc;
    }
    __syncthreads();
    x += wsum[wid];
    if (idx < N_NODES) rowptr[idx + 1] = x;
}

__global__ void k_scan2(int* __restrict__ bsum, int nb) {
    int t = threadIdx.x;
    int orig = (t < nb) ? bsum[t] : 0;
    int x = orig;
    int lane = t & 63, wid = t >> 6;
    __shared__ int wsum[4];
    #pragma unroll
    for (int off = 1; off < 64; off <<= 1) {
        int y = __shfl_up(x, off, 64);
        if (lane >= off) x += y;
    }
    if (lane == 63) wsum[wid] = x;
    __syncthreads();
    if (t == 0) {
        int acc = 0;
        #pragma unroll
        for (int i = 0; i < 4; ++i) { int v = wsum[i]; wsum[i] = acc; acc += v; }
    }
    __syncthreads();
    x += wsum[wid];
    if (t < nb) bsum[t] = x - orig;
}

__global__ void k_scan3(int* __restrict__ rowptr, const int* __restrict__ bsum) {
    int b = blockIdx.x, t = threadIdx.x;
    int idx = b * 256 + t;
    if (idx < N_NODES) rowptr[idx + 1] += bsum[b];
    if (idx == 0) rowptr[0] = 0;
}

__global__ void k_fill(const int* __restrict__ src, const int* __restrict__ tgt,
                       const int* __restrict__ etype, const int* __restrict__ etime,
                       const int* __restrict__ ntype, int* __restrict__ cursor,
                       int* __restrict__ sE, int* __restrict__ attr,
                       int* __restrict__ gE) {
    int e = blockIdx.x * 256 + threadIdx.x;
    if (e >= N_EDGES) return;
    int g = tgt[e];
    int s = src[e];
    int r = etype[e];
    int tm = etime[e];
    int t = ntype[s];
    int p = atomicAdd(&cursor[g], 1);
    sE[p] = s;
    attr[p] = (r << 12) | (tm * TT + t);
    gE[p] = g;
}

// -------------------- node-level linears (type-binned) --------------------

// transposed-staging version (32 nodes/block, float4 LDS broadcast rows)
__global__ __launch_bounds__(128) void k_adapter(
        const float* __restrict__ x, const int* __restrict__ cnt,
        const int* __restrict__ lists,
        const float* __restrict__ W, const float* __restrict__ b,
        float* __restrict__ h) {
    int t = blockIdx.y;
    int c = cnt[t];
    int i0 = blockIdx.x * NPB2;
    if (i0 >= c) return;
    int j = threadIdx.x;
    __shared__ int nidx[NPB2];
    __shared__ float xsT[DIN_][36];   // 23.9 KB, rows 144 B
    if (j < NPB2) nidx[j] = (i0 + j < c) ? lists[t * N_NODES + i0 + j] : -1;
    __syncthreads();
    for (int m = 0; m < NPB2; ++m) {
        int n = nidx[m];
        const float* xr = x + (size_t)(n < 0 ? 0 : n) * DIN_;
        float v0 = (n >= 0) ? xr[j] : 0.f;
        xsT[j][m] = v0;
        if (j + 128 < DIN_) {
            float v1 = (n >= 0) ? xr[j + 128] : 0.f;
            xsT[j + 128][m] = v1;
        }
    }
    __syncthreads();
    const float* Wt = W + (size_t)t * DIN_ * NHID;
    float bj = b[t * NHID + j];
    float acc[NPB2];
    #pragma unroll
    for (int m = 0; m < NPB2; ++m) acc[m] = bj;
    for (int d = 0; d < DIN_; ++d) {
        float w = Wt[d * NHID + j];
        const float4* xrow = (const float4*)&xsT[d][0];
        #pragma unroll
        for (int cc = 0; cc < 8; ++cc) {
            float4 x4 = xrow[cc];
            int mb = cc * 4;
            acc[mb+0] = fmaf(x4.x, w, acc[mb+0]);
            acc[mb+1] = fmaf(x4.y, w, acc[mb+1]);
            acc[mb+2] = fmaf(x4.z, w, acc[mb+2]);
            acc[mb+3] = fmaf(x4.w, w, acc[mb+3]);
        }
    }
    #pragma unroll
    for (int m = 0; m < NPB2; ++m) {
        int n = nidx[m];
        if (n >= 0) h[(size_t)n * NHID + j] = tanhf(acc[m]);
    }
}

// Fused: hk/hv (fp16 gather tables) + u3 = rel_att[r] @ q (fp16 out).
__global__ __launch_bounds__(128) void k_node_lin(
        const float* __restrict__ h, const int* __restrict__ cnt,
        const int* __restrict__ lists,
        const float* __restrict__ Wk, const float* __restrict__ bk,
        const float* __restrict__ Wq, const float* __restrict__ bq,
        const float* __restrict__ Wv, const float* __restrict__ bv,
        const float* __restrict__ rel_att,
        __half* __restrict__ hk16, __half* __restrict__ hv16,
        __half* __restrict__ u316) {
    int t = blockIdx.y;
    int c = cnt[t];
    int i0 = blockIdx.x * NPB2;
    if (i0 >= c) return;
    int j = threadIdx.x;
    __shared__ int nidx[NPB2];
    __shared__ float hsT[NHID][36];   // rows 144 B (16B-aligned)
    float (*aqs)[132] = (float(*)[132])&hsT[0][0];

    if (j < NPB2) nidx[j] = (i0 + j < c) ? lists[t * N_NODES + i0 + j] : -1;
    __syncthreads();
    for (int m = 0; m < NPB2; ++m) {
        int n = nidx[m];
        hsT[j][m] = (n >= 0) ? h[(size_t)n * NHID + j] : 0.f;
    }
    __syncthreads();

    const float* WkT = Wk + (size_t)t * NHID * NHID;
    const float* WqT = Wq + (size_t)t * NHID * NHID;
    const float* WvT = Wv + (size_t)t * NHID * NHID;
    float ak[NPB2], aq[NPB2], av[NPB2];
    float bkj = bk[t * NHID + j], bqj = bq[t * NHID + j], bvj = bv[t * NHID + j];
    #pragma unroll
    for (int m = 0; m < NPB2; ++m) { ak[m] = bkj; aq[m] = bqj; av[m] = bvj; }
    for (int i = 0; i < NHID; ++i) {
        float wk = WkT[i * NHID + j];
        float wq = WqT[i * NHID + j];
        float wv = WvT[i * NHID + j];
        const float4* hrow = (const float4*)&hsT[i][0];
        #pragma unroll
        for (int cc = 0; cc < 8; ++cc) {
            float4 h4 = hrow[cc];
            int mb = cc * 4;
            ak[mb+0] = fmaf(h4.x, wk, ak[mb+0]);
            ak[mb+1] = fmaf(h4.y, wk, ak[mb+1]);
            ak[mb+2] = fmaf(h4.z, wk, ak[mb+2]);
            ak[mb+3] = fmaf(h4.w, wk, ak[mb+3]);
            aq[mb+0] = fmaf(h4.x, wq, aq[mb+0]);
            aq[mb+1] = fmaf(h4.y, wq, aq[mb+1]);
            aq[mb+2] = fmaf(h4.z, wq, aq[mb+2]);
            aq[mb+3] = fmaf(h4.w, wq, aq[mb+3]);
            av[mb+0] = fmaf(h4.x, wv, av[mb+0]);
            av[mb+1] = fmaf(h4.y, wv, av[mb+1]);
            av[mb+2] = fmaf(h4.z, wv, av[mb+2]);
            av[mb+3] = fmaf(h4.w, wv, av[mb+3]);
        }
    }
    #pragma unroll
    for (int m = 0; m < NPB2; ++m) {
        int n = nidx[m];
        if (n >= 0) {
            hk16[(size_t)n * NHID + j] = __float2half(ak[m]);
            hv16[(size_t)n * NHID + j] = __float2half(av[m]);
        }
    }
    __syncthreads();
    for (int m = 0; m < NPB2; ++m) aqs[m][j] = aq[m];
    __syncthreads();

    // qrel: u3[n,r][h*16+f] = sum_x rel_att[r][h][f][x] * q[n][h*16+x]
    int hh = j >> 4, f = j & 15;
    float A[RR][DKH];
    #pragma unroll
    for (int r = 0; r < RR; ++r) {
        const float4* Arow = (const float4*)(rel_att + (((r * HH + hh) << 8) | (f * 16)));
        #pragma unroll
        for (int cc = 0; cc < 4; ++cc) {
            float4 a4 = Arow[cc];
            A[r][cc*4+0] = a4.x; A[r][cc*4+1] = a4.y;
            A[r][cc*4+2] = a4.z; A[r][cc*4+3] = a4.w;
        }
    }
    for (int m = 0; m < NPB2; ++m) {
        int n = nidx[m];
        if (n < 0) continue;
        const float4* arow = (const float4*)&aqs[m][hh * 16];
        float qv[DKH];
        #pragma unroll
        for (int cc = 0; cc < 4; ++cc) {
            float4 q4 = arow[cc];
            qv[cc*4+0] = q4.x; qv[cc*4+1] = q4.y;
            qv[cc*4+2] = q4.z; qv[cc*4+3] = q4.w;
        }
        #pragma unroll
        for (int r = 0; r < RR; ++r) {
            float u = 0.f;
            #pragma unroll
            for (int d = 0; d < DKH; ++d) u = fmaf(A[r][d], qv[d], u);
            u316[((size_t)n * RR + r) * NHID + j] = __float2half(u);
        }
    }
}

__global__ __launch_bounds__(128) void k_out(
        const __half* __restrict__ agg16, const float* __restrict__ hin,
        const int* __restrict__ cnt, const int* __restrict__ lists,
        const float* __restrict__ aW, const float* __restrict__ ab,
        const float* __restrict__ skp, float* __restrict__ hout) {
    int t = blockIdx.y;
    int c = cnt[t];
    int i0 = blockIdx.x * NPB2;
    if (i0 >= c) return;
    int j = threadIdx.x;
    __shared__ int nidx[NPB2];
    __shared__ float gsT[NHID][36];
    if (j < NPB2) nidx[j] = (i0 + j < c) ? lists[t * N_NODES + i0 + j] : -1;
    __syncthreads();
    for (int m = 0; m < NPB2; ++m) {
        int n = nidx[m];
        float xv = (n >= 0) ? __half2float(agg16[(size_t)n * NHID + j]) : 0.f;
        gsT[j][m] = 0.5f * xv * (1.f + erff(xv * 0.7071067811865476f));
    }
    __syncthreads();
    const float* Wt = aW + (size_t)t * NHID * NHID;
    float bj = ab[t * NHID + j];
    float acc[NPB2];
    #pragma unroll
    for (int m = 0; m < NPB2; ++m) acc[m] = bj;
    for (int i = 0; i < NHID; ++i) {
        float w = Wt[i * NHID + j];
        const float4* grow = (const float4*)&gsT[i][0];
        #pragma unroll
        for (int cc = 0; cc < 8; ++cc) {
            float4 g4 = grow[cc];
            int mb = cc * 4;
            acc[mb+0] = fmaf(g4.x, w, acc[mb+0]);
            acc[mb+1] = fmaf(g4.y, w, acc[mb+1]);
            acc[mb+2] = fmaf(g4.z, w, acc[mb+2]);
            acc[mb+3] = fmaf(g4.w, w, acc[mb+3]);
        }
    }
    float alpha = 1.f / (1.f + expf(-skp[t]));
    #pragma unroll
    for (int m = 0; m < NPB2; ++m) {
        int n = nidx[m];
        if (n >= 0)
            hout[(size_t)n * NHID + j] =
                acc[m] * alpha + hin[(size_t)n * NHID + j] * (1.f - alpha);
    }
}

// -------------------- RTE projection (proj fused in) --------------------

__global__ void k_rkv(const float* __restrict__ tab, const float* __restrict__ rteW,
                      const float* __restrict__ rteb,
                      const float* __restrict__ kW, const float* __restrict__ vW,
                      __half* __restrict__ RK16, float* __restrict__ RV) {
    int p = blockIdx.x, t = blockIdx.y;
    int j = threadIdx.x;
    __shared__ float ts[NHID];
    __shared__ float ps[NHID];
    ts[j] = tab[p * NHID + j];
    __syncthreads();
    float pj = rteb[j];
    for (int i = 0; i < NHID; ++i) pj = fmaf(ts[i], rteW[i * NHID + j], pj);
    ps[j] = pj;
    __syncthreads();
    const float* Wk = kW + (size_t)t * NHID * NHID;
    const float* Wv = vW + (size_t)t * NHID * NHID;
    float ak = 0.f, av = 0.f;
    for (int i = 0; i < NHID; ++i) {
        float pi = ps[i];
        ak = fmaf(pi, Wk[i * NHID + j], ak);
        av = fmaf(pi, Wv[i * NHID + j], av);
    }
    RK16[((size_t)p * TT + t) * NHID + j] = __float2half(ak);
    RV[((size_t)p * TT + t) * NHID + j] = av;
}

// -------------------- edge pass 1: attention scores (2 edges/thread) -------

__global__ __launch_bounds__(256) void k_att(
        const __half* __restrict__ hk16, const __half* __restrict__ u316,
        const __half* __restrict__ RK16,
        const int* __restrict__ sE, const int* __restrict__ attr,
        const int* __restrict__ gE,
        const float* __restrict__ rel_pri, float* __restrict__ att2) {
    int idx = blockIdx.x * 256 + threadIdx.x;
    if (idx >= (N_EDGES / 2) * HH) return;
    int p = idx >> 3, h = idx & 7;
    int k0 = p * 2;
    int2 ss = *(const int2*)(sE + k0);
    int2 aa = *(const int2*)(attr + k0);
    int2 gg = *(const int2*)(gE + k0);
    int r0 = aa.x >> 12, row0 = aa.x & 4095;
    int r1 = aa.y >> 12, row1 = aa.y & 4095;
    const __half2* hkA = (const __half2*)hk16 + (size_t)ss.x * 64 + h * 8;
    const __half2* rkA = (const __half2*)RK16 + (size_t)row0 * 64 + h * 8;
    const __half2* uA  = (const __half2*)u316 + ((size_t)gg.x * RR + r0) * 64 + h * 8;
    const __half2* hkB = (const __half2*)hk16 + (size_t)ss.y * 64 + h * 8;
    const __half2* rkB = (const __half2*)RK16 + (size_t)row1 * 64 + h * 8;
    const __half2* uB  = (const __half2*)u316 + ((size_t)gg.y * RR + r1) * 64 + h * 8;
    float accA = 0.f, accB = 0.f;
    #pragma unroll
    for (int i = 0; i < 8; ++i) {
        float2 pa = __half22float2(hkA[i]);
        float2 ra = __half22float2(rkA[i]);
        float2 ua = __half22float2(uA[i]);
        accA = fmaf(pa.x + ra.x, ua.x, accA);
        accA = fmaf(pa.y + ra.y, ua.y, accA);
        float2 pb = __half22float2(hkB[i]);
        float2 rb = __half22float2(rkB[i]);
        float2 ub = __half22float2(uB[i]);
        accB = fmaf(pb.x + rb.x, ub.x, accB);
        accB = fmaf(pb.y + rb.y, ub.y, accB);
    }
    accA *= rel_pri[r0 * HH + h] * 0.25f;
    accB *= rel_pri[r1 * HH + h] * 0.25f;
    *(float2*)(att2 + (size_t)h * N_EDGES + k0) = make_float2(accA, accB);
}

// -------------------- edge pass 2: CSR softmax + aggregate (4-wide ILP) ----

__global__ __launch_bounds__(128) void k_csr(
        const __half* __restrict__ hv16, const float* __restrict__ RV,
        float* __restrict__ att2,
        const int* __restrict__ rowptr, const int* __restrict__ sE,
        const int* __restrict__ attr,
        const float* __restrict__ rel_msg, __half* __restrict__ agg16) {
    int n = blockIdx.x;
    int tid = threadIdx.x;
    int h = tid >> 4, f = tid & 15;
    int beg = rowptr[n], end = rowptr[n + 1];
    float* ap = att2 + (size_t)h * N_EDGES;

    float m = -FLT_MAX;
    for (int k = beg + f; k < end; k += 16) m = fmaxf(m, ap[k]);
    #pragma unroll
    for (int mask = 1; mask <= 8; mask <<= 1)
        m = fmaxf(m, __shfl_xor(m, mask, 64));

    float ssum = 0.f;
    for (int k = beg + f; k < end; k += 16) {
        float ex = expf(ap[k] - m);
        ap[k] = ex;
        ssum += ex;
    }
    #pragma unroll
    for (int mask = 1; mask <= 8; mask <<= 1)
        ssum += __shfl_xor(ssum, mask, 64);
    float rden = 1.f / fmaxf(ssum, 1e-9f);
    __syncthreads();

    float a0 = 0.f, a1 = 0.f, a2 = 0.f, a3 = 0.f;
    int k = beg;
    for (; k + 4 <= end; k += 4) {
        int s0 = sE[k],   s1 = sE[k+1], s2 = sE[k+2], s3 = sE[k+3];
        int t0 = attr[k], t1 = attr[k+1], t2 = attr[k+2], t3 = attr[k+3];
        float w0 = ap[k], w1 = ap[k+1], w2 = ap[k+2], w3 = ap[k+3];
        float v0 = __half2float(hv16[(size_t)s0 * NHID + tid]) + RV[(size_t)(t0 & 4095) * NHID + tid];
        float v1 = __half2float(hv16[(size_t)s1 * NHID + tid]) + RV[(size_t)(t1 & 4095) * NHID + tid];
        float v2 = __half2float(hv16[(size_t)s2 * NHID + tid]) + RV[(size_t)(t2 & 4095) * NHID + tid];
        float v3 = __half2float(hv16[(size_t)s3 * NHID + tid]) + RV[(size_t)(t3 & 4095) * NHID + tid];
        float wv0 = w0 * v0, wv1 = w1 * v1, wv2 = w2 * v2, wv3 = w3 * v3;
        int r0 = t0 >> 12, r1 = t1 >> 12, r2 = t2 >> 12, r3 = t3 >> 12;
        a0 += ((r0 == 0) ? wv0 : 0.f) + ((r1 == 0) ? wv1 : 0.f)
            + ((r2 == 0) ? wv2 : 0.f) + ((r3 == 0) ? wv3 : 0.f);
        a1 += ((r0 == 1) ? wv0 : 0.f) + ((r1 == 1) ? wv1 : 0.f)
            + ((r2 == 1) ? wv2 : 0.f) + ((r3 == 1) ? wv3 : 0.f);
        a2 += ((r0 == 2) ? wv0 : 0.f) + ((r1 == 2) ? wv1 : 0.f)
            + ((r2 == 2) ? wv2 : 0.f) + ((r3 == 2) ? wv3 : 0.f);
        a3 += ((r0 == 3) ? wv0 : 0.f) + ((r1 == 3) ? wv1 : 0.f)
            + ((r2 == 3) ? wv2 : 0.f) + ((r3 == 3) ? wv3 : 0.f);
    }
    for (; k < end; ++k) {
        int s = sE[k];
        int a = attr[k];
        float vvt = __half2float(hv16[(size_t)s * NHID + tid])
                    + RV[(size_t)(a & 4095) * NHID + tid];
        float wv = ap[k] * vvt;
        int r = a >> 12;
        a0 += (r == 0) ? wv : 0.f;
        a1 += (r == 1) ? wv : 0.f;
        a2 += (r == 2) ? wv : 0.f;
        a3 += (r == 3) ? wv : 0.f;
    }

    int lanebase = tid & 48;
    float out = 0.f;
    #pragma unroll
    for (int r = 0; r < RR; ++r) {
        float ar = (r == 0) ? a0 : (r == 1) ? a1 : (r == 2) ? a2 : a3;
        const float* M = rel_msg + ((r * HH + h) << 8) + f;
        #pragma unroll
        for (int d = 0; d < DKH; ++d) {
            float vd = __shfl(ar, lanebase + d, 64);
            out = fmaf(vd, M[d * 16], out);
        }
    }
    agg16[(size_t)n * NHID + tid] = __float2half(out * rden);
}

// -------------------- launch --------------------

extern "C" void kernel_launch(void* const* d_in, const int* in_sizes, int n_in,
                              void* d_out, int out_size, void* d_ws, size_t ws_size,
                              hipStream_t stream) {
    const float* node_feature = (const float*)d_in[0];
    const int*   node_type    = (const int*)d_in[1];
    const int*   edge_time    = (const int*)d_in[2];
    const int*   edge_index   = (const int*)d_in[3];
    const int*   edge_type    = (const int*)d_in[4];
    const float* adapt_W = (const float*)d_in[5];
    const float* adapt_b = (const float*)d_in[6];
    const float* kW = (const float*)d_in[7];
    const float* kb = (const float*)d_in[8];
    const float* qW = (const float*)d_in[9];
    const float* qb = (const float*)d_in[10];
    const float* vW = (const float*)d_in[11];
    const float* vb = (const float*)d_in[12];
    const float* aW = (const float*)d_in[13];
    const float* ab = (const float*)d_in[14];
    const float* rel_att = (const float*)d_in[15];
    const float* rel_msg = (const float*)d_in[16];
    const float* rel_pri = (const float*)d_in[17];
    const float* skip = (const float*)d_in[18];
    const float* rteW = (const float*)d_in[19];
    const float* rteb = (const float*)d_in[20];

    const int* src = edge_index;             // edge_index[0][:]
    const int* tgt = edge_index + N_EDGES;   // edge_index[1][:]

    float* ws = (float*)d_ws;
    float* hA   = ws; ws += (size_t)N_NODES * NHID;
    float* att2 = ws; ws += (size_t)N_EDGES * HH;
    float* tab  = ws; ws += MAXT_ * NHID;
    float* RV   = ws; ws += MAXT_ * TT * NHID;
    __half* u316  = (__half*)ws; ws += (size_t)N_NODES * RR * NHID / 2;
    __half* agg16 = (__half*)ws; ws += (size_t)N_NODES * NHID / 2;
    __half* hk16  = (__half*)ws; ws += (size_t)N_NODES * NHID / 2;
    __half* hv16  = (__half*)ws; ws += (size_t)N_NODES * NHID / 2;
    __half* RK16  = (__half*)ws; ws += (size_t)MAXT_ * TT * NHID / 2;
    int*   deg    = (int*)ws; ws += N_NODES;
    int*   rowptr = (int*)ws; ws += N_NODES + 2;   // pad keeps 8B alignment below
    int*   cursor = (int*)ws; ws += N_NODES;
    int*   sE     = (int*)ws; ws += N_EDGES;
    int*   attr   = (int*)ws; ws += N_EDGES;
    int*   gE     = (int*)ws; ws += N_EDGES;
    int*   bsum   = (int*)ws; ws += 256;
    int*   cnt    = (int*)ws; ws += 4;
    int*   lists  = (int*)ws; ws += (size_t)TT * N_NODES;

    const int nodeBlocksX2 = (N_NODES + NPB2 - 1) / NPB2;  // 1563
    dim3 nodeGrid2(nodeBlocksX2, TT);
    const int eB = (N_EDGES + 255) / 256;                  // 1954
    const int attBlocks = ((N_EDGES / 2) * HH + 255) / 256;  // 7813
    const int scanBlocks = (N_NODES + 255) / 256;          // 196

    hipMemsetAsync(cnt, 0, 4 * sizeof(int), stream);
    hipMemsetAsync(deg, 0, N_NODES * sizeof(int), stream);
    k_bin<<<(N_NODES + 255) / 256, 256, 0, stream>>>(node_type, cnt, lists);
    k_deg<<<eB, 256, 0, stream>>>(tgt, deg);
    k_scan1<<<scanBlocks, 256, 0, stream>>>(deg, rowptr, bsum);
    k_scan2<<<1, 256, 0, stream>>>(bsum, scanBlocks);
    k_scan3<<<scanBlocks, 256, 0, stream>>>(rowptr, bsum);
    hipMemcpyAsync(cursor, rowptr, N_NODES * sizeof(int),
                   hipMemcpyDeviceToDevice, stream);
    k_fill<<<eB, 256, 0, stream>>>(src, tgt, edge_type, edge_time, node_type,
                                   cursor, sE, attr, gE);

    k_sin_table<<<(MAXT_ * 64 + 255) / 256, 256, 0, stream>>>(tab);
    k_adapter<<<nodeGrid2, 128, 0, stream>>>(node_feature, cnt, lists,
                                             adapt_W, adapt_b, hA);

    for (int l = 0; l < NLAYER; ++l) {
        const float* hin = hA;
        float* hout = (l == 0) ? hA : (float*)d_out;   // layer 0 in-place (per-thread R-then-W)
        const float* kW_l = kW + (size_t)l * TT * NHID * NHID;
        const float* kb_l = kb + (size_t)l * TT * NHID;
        const float* qW_l = qW + (size_t)l * TT * NHID * NHID;
        const float* qb_l = qb + (size_t)l * TT * NHID;
        const float* vW_l = vW + (size_t)l * TT * NHID * NHID;
        const float* vb_l = vb + (size_t)l * TT * NHID;
        const float* aW_l = aW + (size_t)l * TT * NHID * NHID;
        const float* ab_l = ab + (size_t)l * TT * NHID;
        const float* ratt_l = rel_att + (size_t)l * RR * HH * DKH * DKH;
        const float* rmsg_l = rel_msg + (size_t)l * RR * HH * DKH * DKH;
        const float* rpri_l = rel_pri + (size_t)l * RR * HH;
        const float* skip_l = skip + (size_t)l * TT;
        const float* rteW_l = rteW + (size_t)l * NHID * NHID;
        const float* rteb_l = rteb + (size_t)l * NHID;

        dim3 rkvGrid(MAXT_, TT);
        k_rkv<<<rkvGrid, 128, 0, stream>>>(tab, rteW_l, rteb_l, kW_l, vW_l, RK16, RV);
        k_node_lin<<<nodeGrid2, 128, 0, stream>>>(hin, cnt, lists,
                                                  kW_l, kb_l, qW_l, qb_l, vW_l, vb_l,
                                                  ratt_l, hk16, hv16, u316);
        k_att<<<attBlocks, 256, 0, stream>>>(hk16, u316, RK16, sE, attr, gE,
                                             rpri_l, att2);
        k_csr<<<N_NODES, 128, 0, stream>>>(hv16, RV, att2, rowptr, sE, attr,
                                           rmsg_l, agg16);
        k_out<<<nodeGrid2, 128, 0, stream>>>(agg16, hin, cnt, lists, aW_l, ab_l,
                                             skip_l, hout);
    }
}